// Round 1
// baseline (958.056 us; speedup 1.0000x reference)
//
#include <hip/hip_runtime.h>

#define LN_EPS 1e-5f

// ---------------- degree / dinv ----------------
__global__ void k_deg_init(float* __restrict__ deg, int N) {
    int i = blockIdx.x * blockDim.x + threadIdx.x;
    if (i < N) deg[i] = 1.0f;  // self-loop
}

__global__ void k_deg_count(const int* __restrict__ dst, float* __restrict__ deg, int E) {
    int i = blockIdx.x * blockDim.x + threadIdx.x;
    int stride = gridDim.x * blockDim.x;
    for (int e = i; e < E; e += stride)
        unsafeAtomicAdd(&deg[dst[e]], 1.0f);
}

__global__ void k_dinv(float* __restrict__ deg, int N) {  // in-place deg -> rsqrt(deg)
    int i = blockIdx.x * blockDim.x + threadIdx.x;
    if (i < N) deg[i] = rsqrtf(deg[i]);
}

// ---------------- dense GEMM: C[N][64] = A[N][64] @ W[64][64] (+bias, relu) ----------------
template <bool RELU_BIAS>
__global__ __launch_bounds__(256) void k_gemm64(const float* __restrict__ A,
                                                const float* __restrict__ W,
                                                const float* __restrict__ bias,
                                                float* __restrict__ C, int N) {
    __shared__ __align__(16) float As[64][68];
    __shared__ __align__(16) float Ws[64][68];
    int tid = threadIdx.x;
    int n0 = blockIdx.x * 64;

    #pragma unroll
    for (int p = 0; p < 4; ++p) {
        int flat = p * 1024 + tid * 4;
        int r = flat >> 6, c = flat & 63;
        float4 w = *reinterpret_cast<const float4*>(W + flat);
        *reinterpret_cast<float4*>(&Ws[r][c]) = w;
        int node = n0 + r;
        float4 a = make_float4(0.f, 0.f, 0.f, 0.f);
        if (node < N) a = *reinterpret_cast<const float4*>(A + (size_t)node * 64 + c);
        *reinterpret_cast<float4*>(&As[r][c]) = a;
    }
    __syncthreads();

    int tx = tid & 15;   // feature group: f0 = tx*4
    int ty = tid >> 4;   // node group:    n  = ty*4 + ni
    float acc[4][4];
    #pragma unroll
    for (int i = 0; i < 4; ++i)
        #pragma unroll
        for (int j = 0; j < 4; ++j) acc[i][j] = 0.f;

    #pragma unroll
    for (int k4 = 0; k4 < 16; ++k4) {
        float4 a[4], w[4];
        #pragma unroll
        for (int ni = 0; ni < 4; ++ni)
            a[ni] = *reinterpret_cast<const float4*>(&As[ty * 4 + ni][k4 * 4]);
        #pragma unroll
        for (int j = 0; j < 4; ++j)
            w[j] = *reinterpret_cast<const float4*>(&Ws[k4 * 4 + j][tx * 4]);
        #pragma unroll
        for (int ni = 0; ni < 4; ++ni) {
            const float* av = reinterpret_cast<const float*>(&a[ni]);
            #pragma unroll
            for (int j = 0; j < 4; ++j) {
                float ak = av[j];
                acc[ni][0] += ak * w[j].x;
                acc[ni][1] += ak * w[j].y;
                acc[ni][2] += ak * w[j].z;
                acc[ni][3] += ak * w[j].w;
            }
        }
    }

    float4 bv = make_float4(0.f, 0.f, 0.f, 0.f);
    if (RELU_BIAS) bv = *reinterpret_cast<const float4*>(bias + tx * 4);
    #pragma unroll
    for (int ni = 0; ni < 4; ++ni) {
        int node = n0 + ty * 4 + ni;
        if (node < N) {
            float4 c;
            c.x = acc[ni][0]; c.y = acc[ni][1]; c.z = acc[ni][2]; c.w = acc[ni][3];
            if (RELU_BIAS) {
                c.x = fmaxf(c.x + bv.x, 0.f);
                c.y = fmaxf(c.y + bv.y, 0.f);
                c.z = fmaxf(c.z + bv.z, 0.f);
                c.w = fmaxf(c.w + bv.w, 0.f);
            }
            *reinterpret_cast<float4*>(C + (size_t)node * 64 + tx * 4) = c;
        }
    }
}

// ---------------- self-loop init: AGG = H * dinv^2 ----------------
__global__ void k_selfinit(const float* __restrict__ H, const float* __restrict__ dinv,
                           float* __restrict__ AGG, int N) {
    int idx = blockIdx.x * blockDim.x + threadIdx.x;  // over N*16 float4s
    if (idx >= N * 16) return;
    int node = idx >> 4;
    float di = dinv[node];
    float c = di * di;
    float4 h = *reinterpret_cast<const float4*>(H + (size_t)idx * 4);
    float4 o;
    o.x = h.x * c; o.y = h.y * c; o.z = h.z * c; o.w = h.w * c;
    *reinterpret_cast<float4*>(AGG + (size_t)idx * 4) = o;
}

// ---------------- edge scatter: AGG[dst] += H[src] * dinv[src]*dinv[dst] ----------------
__global__ void k_scatter(const float* __restrict__ H, const int* __restrict__ src,
                          const int* __restrict__ dst, const float* __restrict__ dinv,
                          float* __restrict__ AGG, int E) {
    int wave = (blockIdx.x * blockDim.x + threadIdx.x) >> 6;
    int lane = threadIdx.x & 63;
    int nwaves = (gridDim.x * blockDim.x) >> 6;
    for (int e = wave; e < E; e += nwaves) {
        int s = src[e];
        int d = dst[e];
        float coef = dinv[s] * dinv[d];
        float v = H[(size_t)s * 64 + lane] * coef;
        unsafeAtomicAdd(&AGG[(size_t)d * 64 + lane], v);
    }
}

// ---------------- fused bias + relu + layernorm (thread per node) ----------------
__global__ void k_postln(const float* __restrict__ AGG, const float* __restrict__ b,
                         const float* __restrict__ g, const float* __restrict__ beta,
                         float* __restrict__ out, int N) {
    __shared__ float sb[64], sg[64], sbe[64];
    if (threadIdx.x < 64) {
        sb[threadIdx.x] = b[threadIdx.x];
        sg[threadIdx.x] = g[threadIdx.x];
        sbe[threadIdx.x] = beta[threadIdx.x];
    }
    __syncthreads();
    int i = blockIdx.x * blockDim.x + threadIdx.x;
    if (i >= N) return;
    float v[64];
    const float4* in4 = reinterpret_cast<const float4*>(AGG + (size_t)i * 64);
    #pragma unroll
    for (int q = 0; q < 16; ++q) {
        float4 t = in4[q];
        v[q * 4 + 0] = t.x; v[q * 4 + 1] = t.y; v[q * 4 + 2] = t.z; v[q * 4 + 3] = t.w;
    }
    float mu = 0.f;
    #pragma unroll
    for (int k = 0; k < 64; ++k) {
        v[k] = fmaxf(v[k] + sb[k], 0.f);
        mu += v[k];
    }
    mu *= (1.f / 64.f);
    float var = 0.f;
    #pragma unroll
    for (int k = 0; k < 64; ++k) {
        float d = v[k] - mu;
        var += d * d;
    }
    var *= (1.f / 64.f);
    float r = rsqrtf(var + LN_EPS);
    float4* out4 = reinterpret_cast<float4*>(out + (size_t)i * 64);
    #pragma unroll
    for (int q = 0; q < 16; ++q) {
        float4 o;
        o.x = (v[q * 4 + 0] - mu) * r * sg[q * 4 + 0] + sbe[q * 4 + 0];
        o.y = (v[q * 4 + 1] - mu) * r * sg[q * 4 + 1] + sbe[q * 4 + 1];
        o.z = (v[q * 4 + 2] - mu) * r * sg[q * 4 + 2] + sbe[q * 4 + 2];
        o.w = (v[q * 4 + 3] - mu) * r * sg[q * 4 + 3] + sbe[q * 4 + 3];
        out4[q] = o;
    }
}

// ---------------- final: out[N][3] = H[N][64] @ Wm2[64][3] + bm2 ----------------
__global__ void k_mlp_out(const float* __restrict__ H, const float* __restrict__ Wm2,
                          const float* __restrict__ bm2, float* __restrict__ out, int N) {
    __shared__ float Ws[192];
    __shared__ float bs[3];
    if (threadIdx.x < 192) Ws[threadIdx.x] = Wm2[threadIdx.x];
    if (threadIdx.x < 3) bs[threadIdx.x] = bm2[threadIdx.x];
    __syncthreads();
    int i = blockIdx.x * blockDim.x + threadIdx.x;
    if (i >= N) return;
    float a0 = 0.f, a1 = 0.f, a2 = 0.f;
    const float4* h4 = reinterpret_cast<const float4*>(H + (size_t)i * 64);
    #pragma unroll
    for (int q = 0; q < 16; ++q) {
        float4 h = h4[q];
        float hv[4] = {h.x, h.y, h.z, h.w};
        #pragma unroll
        for (int j = 0; j < 4; ++j) {
            int k = q * 4 + j;
            a0 += hv[j] * Ws[k * 3 + 0];
            a1 += hv[j] * Ws[k * 3 + 1];
            a2 += hv[j] * Ws[k * 3 + 2];
        }
    }
    out[(size_t)i * 3 + 0] = a0 + bs[0];
    out[(size_t)i * 3 + 1] = a1 + bs[1];
    out[(size_t)i * 3 + 2] = a2 + bs[2];
}

extern "C" void kernel_launch(void* const* d_in, const int* in_sizes, int n_in,
                              void* d_out, int out_size, void* d_ws, size_t ws_size,
                              hipStream_t stream) {
    const float* z     = (const float*)d_in[0];
    const int*   ei    = (const int*)d_in[1];
    const float* W1    = (const float*)d_in[2];
    const float* b1    = (const float*)d_in[3];
    const float* g1    = (const float*)d_in[4];
    const float* beta1 = (const float*)d_in[5];
    const float* W2    = (const float*)d_in[6];
    const float* b2    = (const float*)d_in[7];
    const float* g2    = (const float*)d_in[8];
    const float* beta2 = (const float*)d_in[9];
    const float* Wm1   = (const float*)d_in[10];
    const float* bm1   = (const float*)d_in[11];
    const float* Wm2   = (const float*)d_in[12];
    const float* bm2   = (const float*)d_in[13];

    int N = in_sizes[0] / 64;
    int E = in_sizes[1] / 2;
    const int* src = ei;
    const int* dst = ei + E;
    float* out = (float*)d_out;

    float* ws = (float*)d_ws;
    size_t Nr  = ((size_t)N + 63) & ~(size_t)63;   // round for alignment
    size_t N64 = (size_t)N * 64;
    float* dinv = ws;          // N (deg then dinv in-place)
    float* B1 = ws + Nr;       // N*64
    float* B2 = B1 + N64;      // N*64
    float* B3 = B2 + N64;      // N*64

    int nb_n   = (N + 255) / 256;
    int nb_g   = (N + 63) / 64;
    int nb_v4  = (N * 16 + 255) / 256;

    // degree + dinv
    k_deg_init<<<nb_n, 256, 0, stream>>>(dinv, N);
    k_deg_count<<<1024, 256, 0, stream>>>(dst, dinv, E);
    k_dinv<<<nb_n, 256, 0, stream>>>(dinv, N);

    // layer 1
    k_gemm64<false><<<nb_g, 256, 0, stream>>>(z, W1, nullptr, B1, N);
    k_selfinit<<<nb_v4, 256, 0, stream>>>(B1, dinv, B2, N);
    k_scatter<<<2048, 256, 0, stream>>>(B1, src, dst, dinv, B2, E);
    k_postln<<<nb_n, 256, 0, stream>>>(B2, b1, g1, beta1, B3, N);

    // layer 2
    k_gemm64<false><<<nb_g, 256, 0, stream>>>(B3, W2, nullptr, B1, N);
    k_selfinit<<<nb_v4, 256, 0, stream>>>(B1, dinv, B2, N);
    k_scatter<<<2048, 256, 0, stream>>>(B1, src, dst, dinv, B2, E);
    k_postln<<<nb_n, 256, 0, stream>>>(B2, b2, g2, beta2, B3, N);

    // MLP head
    k_gemm64<true><<<nb_g, 256, 0, stream>>>(B3, Wm1, bm1, B1, N);
    k_mlp_out<<<nb_n, 256, 0, stream>>>(B1, Wm2, bm2, out, N);
}

// Round 2
// 620.877 us; speedup vs baseline: 1.5431x; 1.5431x over previous
//
#include <hip/hip_runtime.h>

#define LN_EPS 1e-5f

// ================= CSR build =================
__global__ void k_zero(int* __restrict__ cnt, int N) {
    int i = blockIdx.x * blockDim.x + threadIdx.x;
    if (i < N) cnt[i] = 0;
}

__global__ void k_count(const int* __restrict__ dst, int* __restrict__ cnt, int E) {
    int i = blockIdx.x * blockDim.x + threadIdx.x;
    int stride = gridDim.x * blockDim.x;
    for (int e = i; e < E; e += stride)
        atomicAdd(&cnt[dst[e]], 1);
}

// block b sums cnt[b*1024 .. b*1024+1023] -> bsum[b]
__global__ __launch_bounds__(256) void k_blocksum(const int* __restrict__ cnt,
                                                  int* __restrict__ bsum, int N) {
    __shared__ int sd[256];
    int b = blockIdx.x, t = threadIdx.x;
    int base = b * 1024 + t * 4;
    int s = 0;
    #pragma unroll
    for (int j = 0; j < 4; ++j)
        if (base + j < N) s += cnt[base + j];
    sd[t] = s;
    __syncthreads();
    for (int off = 128; off > 0; off >>= 1) {
        if (t < off) sd[t] += sd[t + off];
        __syncthreads();
    }
    if (t == 0) bsum[b] = sd[0];
}

// single block: exclusive scan of bsum[0..nb), total -> row_ptr[N]
__global__ __launch_bounds__(256) void k_scan_bsums(int* __restrict__ bsum, int nb,
                                                    int* __restrict__ row_ptr, int N) {
    __shared__ int sd[256];
    int t = threadIdx.x;
    int v = (t < nb) ? bsum[t] : 0;
    sd[t] = v;
    __syncthreads();
    for (int off = 1; off < 256; off <<= 1) {
        int x = (t >= off) ? sd[t - off] : 0;
        __syncthreads();
        sd[t] += x;
        __syncthreads();
    }
    if (t < nb) bsum[t] = sd[t] - v;   // exclusive
    if (t == 255) row_ptr[N] = sd[255];
}

// per-chunk exclusive scan + add block offset; also emit cursor copy and dinv
__global__ __launch_bounds__(256) void k_scan_chunk(const int* __restrict__ cnt,
                                                    const int* __restrict__ bsum_scan,
                                                    int* __restrict__ row_ptr,
                                                    int* __restrict__ cursor,
                                                    float* __restrict__ dinv, int N) {
    __shared__ int sd[256];
    int b = blockIdx.x, t = threadIdx.x;
    int idx0 = b * 1024 + t * 4;
    int v[4];
    int s = 0;
    #pragma unroll
    for (int j = 0; j < 4; ++j) {
        v[j] = (idx0 + j < N) ? cnt[idx0 + j] : 0;
        s += v[j];
    }
    sd[t] = s;
    __syncthreads();
    for (int off = 1; off < 256; off <<= 1) {
        int x = (t >= off) ? sd[t - off] : 0;
        __syncthreads();
        sd[t] += x;
        __syncthreads();
    }
    int excl = sd[t] - s + bsum_scan[b];
    #pragma unroll
    for (int j = 0; j < 4; ++j) {
        int i = idx0 + j;
        if (i < N) {
            row_ptr[i] = excl;
            cursor[i] = excl;
            dinv[i] = rsqrtf(1.0f + (float)v[j]);
            excl += v[j];
        }
    }
}

// fill CSR: csr_src[pos]=src, csr_w[pos]=dinv[src]
__global__ void k_fill(const int* __restrict__ src, const int* __restrict__ dst,
                       const float* __restrict__ dinv, int* __restrict__ cursor,
                       int* __restrict__ csr_src, float* __restrict__ csr_w, int E) {
    int i = blockIdx.x * blockDim.x + threadIdx.x;
    int stride = gridDim.x * blockDim.x;
    for (int e = i; e < E; e += stride) {
        int s = src[e];
        int d = dst[e];
        int pos = atomicAdd(&cursor[d], 1);
        csr_src[pos] = s;
        csr_w[pos] = dinv[s];
    }
}

// ================= dense GEMM: C[N][64] = A[N][64] @ W[64][64] (+bias, relu) =================
template <bool RELU_BIAS>
__global__ __launch_bounds__(256) void k_gemm64(const float* __restrict__ A,
                                                const float* __restrict__ W,
                                                const float* __restrict__ bias,
                                                float* __restrict__ C, int N) {
    __shared__ __align__(16) float As[64][68];
    __shared__ __align__(16) float Ws[64][68];
    int tid = threadIdx.x;
    int n0 = blockIdx.x * 64;

    #pragma unroll
    for (int p = 0; p < 4; ++p) {
        int flat = p * 1024 + tid * 4;
        int r = flat >> 6, c = flat & 63;
        float4 w = *reinterpret_cast<const float4*>(W + flat);
        *reinterpret_cast<float4*>(&Ws[r][c]) = w;
        int node = n0 + r;
        float4 a = make_float4(0.f, 0.f, 0.f, 0.f);
        if (node < N) a = *reinterpret_cast<const float4*>(A + (size_t)node * 64 + c);
        *reinterpret_cast<float4*>(&As[r][c]) = a;
    }
    __syncthreads();

    int tx = tid & 15;
    int ty = tid >> 4;
    float acc[4][4];
    #pragma unroll
    for (int i = 0; i < 4; ++i)
        #pragma unroll
        for (int j = 0; j < 4; ++j) acc[i][j] = 0.f;

    #pragma unroll
    for (int k4 = 0; k4 < 16; ++k4) {
        float4 a[4], w[4];
        #pragma unroll
        for (int ni = 0; ni < 4; ++ni)
            a[ni] = *reinterpret_cast<const float4*>(&As[ty * 4 + ni][k4 * 4]);
        #pragma unroll
        for (int j = 0; j < 4; ++j)
            w[j] = *reinterpret_cast<const float4*>(&Ws[k4 * 4 + j][tx * 4]);
        #pragma unroll
        for (int ni = 0; ni < 4; ++ni) {
            const float* av = reinterpret_cast<const float*>(&a[ni]);
            #pragma unroll
            for (int j = 0; j < 4; ++j) {
                float ak = av[j];
                acc[ni][0] += ak * w[j].x;
                acc[ni][1] += ak * w[j].y;
                acc[ni][2] += ak * w[j].z;
                acc[ni][3] += ak * w[j].w;
            }
        }
    }

    float4 bv = make_float4(0.f, 0.f, 0.f, 0.f);
    if (RELU_BIAS) bv = *reinterpret_cast<const float4*>(bias + tx * 4);
    #pragma unroll
    for (int ni = 0; ni < 4; ++ni) {
        int node = n0 + ty * 4 + ni;
        if (node < N) {
            float4 c;
            c.x = acc[ni][0]; c.y = acc[ni][1]; c.z = acc[ni][2]; c.w = acc[ni][3];
            if (RELU_BIAS) {
                c.x = fmaxf(c.x + bv.x, 0.f);
                c.y = fmaxf(c.y + bv.y, 0.f);
                c.z = fmaxf(c.z + bv.z, 0.f);
                c.w = fmaxf(c.w + bv.w, 0.f);
            }
            *reinterpret_cast<float4*>(C + (size_t)node * 64 + tx * 4) = c;
        }
    }
}

// ================= gather + bias + relu + layernorm (wave per node) =================
__global__ __launch_bounds__(256) void k_gather_ln(const float* __restrict__ H,
                                                   const int* __restrict__ row_ptr,
                                                   const int* __restrict__ csr_src,
                                                   const float* __restrict__ csr_w,
                                                   const float* __restrict__ dinv,
                                                   const float* __restrict__ b,
                                                   const float* __restrict__ g,
                                                   const float* __restrict__ beta,
                                                   float* __restrict__ out, int N) {
    int wid = (blockIdx.x * blockDim.x + threadIdx.x) >> 6;
    int lane = threadIdx.x & 63;
    if (wid >= N) return;
    int d = wid;
    float dd = dinv[d];
    float acc = H[(size_t)d * 64 + lane] * dd;   // self loop (w = dd)
    int beg = row_ptr[d], end = row_ptr[d + 1];
    for (int j = beg; j < end; ++j) {
        int s = csr_src[j];
        float w = csr_w[j];
        acc += H[(size_t)s * 64 + lane] * w;
    }
    acc *= dd;
    // bias + relu
    acc = fmaxf(acc + b[lane], 0.f);
    // wave-wide LN over 64 features
    float sum = acc;
    #pragma unroll
    for (int off = 1; off < 64; off <<= 1) sum += __shfl_xor(sum, off);
    float mu = sum * (1.0f / 64.0f);
    float dv = acc - mu;
    float vs = dv * dv;
    #pragma unroll
    for (int off = 1; off < 64; off <<= 1) vs += __shfl_xor(vs, off);
    float r = rsqrtf(vs * (1.0f / 64.0f) + LN_EPS);
    out[(size_t)d * 64 + lane] = dv * r * g[lane] + beta[lane];
}

// ================= final: out[N][3] = H[N][64] @ Wm2[64][3] + bm2 =================
__global__ void k_mlp_out(const float* __restrict__ H, const float* __restrict__ Wm2,
                          const float* __restrict__ bm2, float* __restrict__ out, int N) {
    __shared__ float Ws[192];
    __shared__ float bs[3];
    if (threadIdx.x < 192) Ws[threadIdx.x] = Wm2[threadIdx.x];
    if (threadIdx.x < 3) bs[threadIdx.x] = bm2[threadIdx.x];
    __syncthreads();
    int i = blockIdx.x * blockDim.x + threadIdx.x;
    if (i >= N) return;
    float a0 = 0.f, a1 = 0.f, a2 = 0.f;
    const float4* h4 = reinterpret_cast<const float4*>(H + (size_t)i * 64);
    #pragma unroll
    for (int q = 0; q < 16; ++q) {
        float4 h = h4[q];
        float hv[4] = {h.x, h.y, h.z, h.w};
        #pragma unroll
        for (int j = 0; j < 4; ++j) {
            int k = q * 4 + j;
            a0 += hv[j] * Ws[k * 3 + 0];
            a1 += hv[j] * Ws[k * 3 + 1];
            a2 += hv[j] * Ws[k * 3 + 2];
        }
    }
    out[(size_t)i * 3 + 0] = a0 + bs[0];
    out[(size_t)i * 3 + 1] = a1 + bs[1];
    out[(size_t)i * 3 + 2] = a2 + bs[2];
}

extern "C" void kernel_launch(void* const* d_in, const int* in_sizes, int n_in,
                              void* d_out, int out_size, void* d_ws, size_t ws_size,
                              hipStream_t stream) {
    const float* z     = (const float*)d_in[0];
    const int*   ei    = (const int*)d_in[1];
    const float* W1    = (const float*)d_in[2];
    const float* b1    = (const float*)d_in[3];
    const float* g1    = (const float*)d_in[4];
    const float* beta1 = (const float*)d_in[5];
    const float* W2    = (const float*)d_in[6];
    const float* b2    = (const float*)d_in[7];
    const float* g2    = (const float*)d_in[8];
    const float* beta2 = (const float*)d_in[9];
    const float* Wm1   = (const float*)d_in[10];
    const float* bm1   = (const float*)d_in[11];
    const float* Wm2   = (const float*)d_in[12];
    const float* bm2   = (const float*)d_in[13];

    int N = in_sizes[0] / 64;
    int E = in_sizes[1] / 2;
    const int* src = ei;
    const int* dst = ei + E;
    float* out = (float*)d_out;

    // workspace layout (all 4B elems, chunk-aligned)
    size_t Nr = ((size_t)N + 1023) & ~(size_t)1023;
    size_t Er = ((size_t)E + 3) & ~(size_t)3;
    size_t N64 = (size_t)N * 64;
    int*   cnt     = (int*)d_ws;
    int*   row_ptr = cnt + Nr;          // needs N+1
    int*   cursor  = row_ptr + Nr;
    int*   bsum    = cursor + Nr;       // 1024
    float* dinv    = (float*)(bsum + 1024);
    int*   csr_src = (int*)(dinv + Nr);
    float* csr_w   = (float*)(csr_src + Er);
    float* B1      = csr_w + Er;        // N*64
    float* B3      = B1 + N64;          // N*64

    int nb_n = (N + 255) / 256;
    int nb_g = (N + 63) / 64;
    int nb_c = (N + 1023) / 1024;       // scan chunks
    int nb_w = (N * 64 + 255) / 256;    // wave-per-node grids

    // ---- CSR build ----
    k_zero<<<nb_n, 256, 0, stream>>>(cnt, N);
    k_count<<<1024, 256, 0, stream>>>(dst, cnt, E);
    k_blocksum<<<nb_c, 256, 0, stream>>>(cnt, bsum, N);
    k_scan_bsums<<<1, 256, 0, stream>>>(bsum, nb_c, row_ptr, N);
    k_scan_chunk<<<nb_c, 256, 0, stream>>>(cnt, bsum, row_ptr, cursor, dinv, N);
    k_fill<<<1024, 256, 0, stream>>>(src, dst, dinv, cursor, csr_src, csr_w, E);

    // ---- layer 1 ----
    k_gemm64<false><<<nb_g, 256, 0, stream>>>(z, W1, nullptr, B1, N);
    k_gather_ln<<<nb_w, 256, 0, stream>>>(B1, row_ptr, csr_src, csr_w, dinv,
                                          b1, g1, beta1, B3, N);
    // ---- layer 2 ----
    k_gemm64<false><<<nb_g, 256, 0, stream>>>(B3, W2, nullptr, B1, N);
    k_gather_ln<<<nb_w, 256, 0, stream>>>(B1, row_ptr, csr_src, csr_w, dinv,
                                          b2, g2, beta2, B3, N);
    // ---- MLP head ----
    k_gemm64<true><<<nb_g, 256, 0, stream>>>(B3, Wm1, bm1, B1, N);
    k_mlp_out<<<nb_n, 256, 0, stream>>>(B1, Wm2, bm2, out, N);
}

// Round 3
// 425.733 us; speedup vs baseline: 2.2504x; 1.4584x over previous
//
#include <hip/hip_runtime.h>
#include <hip/hip_bf16.h>

#define LN_EPS 1e-5f
typedef unsigned short u16;

static __device__ __forceinline__ float bf2f(u16 x) {
    return __uint_as_float(((unsigned int)x) << 16);
}
static __device__ __forceinline__ u16 f2bf(float f) {
    unsigned int u = __float_as_uint(f);
    return (u16)((u + 0x7fff + ((u >> 16) & 1)) >> 16);  // RNE
}

// ================= CSR build =================
__global__ void k_zero(int* __restrict__ cnt, int N) {
    int i = blockIdx.x * blockDim.x + threadIdx.x;
    if (i < N) cnt[i] = 0;
}

__global__ void k_count(const int* __restrict__ dst, int* __restrict__ cnt, int E) {
    int i = blockIdx.x * blockDim.x + threadIdx.x;
    int stride = gridDim.x * blockDim.x;
    for (int e = i; e < E; e += stride)
        atomicAdd(&cnt[dst[e]], 1);
}

__global__ __launch_bounds__(256) void k_blocksum(const int* __restrict__ cnt,
                                                  int* __restrict__ bsum, int N) {
    __shared__ int sd[256];
    int b = blockIdx.x, t = threadIdx.x;
    int base = b * 1024 + t * 4;
    int s = 0;
    #pragma unroll
    for (int j = 0; j < 4; ++j)
        if (base + j < N) s += cnt[base + j];
    sd[t] = s;
    __syncthreads();
    for (int off = 128; off > 0; off >>= 1) {
        if (t < off) sd[t] += sd[t + off];
        __syncthreads();
    }
    if (t == 0) bsum[b] = sd[0];
}

__global__ __launch_bounds__(256) void k_scan_bsums(int* __restrict__ bsum, int nb,
                                                    int* __restrict__ row_ptr, int N) {
    __shared__ int sd[256];
    int t = threadIdx.x;
    int v = (t < nb) ? bsum[t] : 0;
    sd[t] = v;
    __syncthreads();
    for (int off = 1; off < 256; off <<= 1) {
        int x = (t >= off) ? sd[t - off] : 0;
        __syncthreads();
        sd[t] += x;
        __syncthreads();
    }
    if (t < nb) bsum[t] = sd[t] - v;
    if (t == 255) row_ptr[N] = sd[255];
}

__global__ __launch_bounds__(256) void k_scan_chunk(const int* __restrict__ cnt,
                                                    const int* __restrict__ bsum_scan,
                                                    int* __restrict__ row_ptr,
                                                    int* __restrict__ cursor,
                                                    float* __restrict__ dinv, int N) {
    __shared__ int sd[256];
    int b = blockIdx.x, t = threadIdx.x;
    int idx0 = b * 1024 + t * 4;
    int v[4];
    int s = 0;
    #pragma unroll
    for (int j = 0; j < 4; ++j) {
        v[j] = (idx0 + j < N) ? cnt[idx0 + j] : 0;
        s += v[j];
    }
    sd[t] = s;
    __syncthreads();
    for (int off = 1; off < 256; off <<= 1) {
        int x = (t >= off) ? sd[t - off] : 0;
        __syncthreads();
        sd[t] += x;
        __syncthreads();
    }
    int excl = sd[t] - s + bsum_scan[b];
    #pragma unroll
    for (int j = 0; j < 4; ++j) {
        int i = idx0 + j;
        if (i < N) {
            row_ptr[i] = excl;
            cursor[i] = excl;
            dinv[i] = rsqrtf(1.0f + (float)v[j]);
            excl += v[j];
        }
    }
}

__global__ void k_fill(const int* __restrict__ src, const int* __restrict__ dst,
                       const float* __restrict__ dinv, int* __restrict__ cursor,
                       int* __restrict__ csr_src, float* __restrict__ csr_w, int E) {
    int i = blockIdx.x * blockDim.x + threadIdx.x;
    int stride = gridDim.x * blockDim.x;
    for (int e = i; e < E; e += stride) {
        int s = src[e];
        int d = dst[e];
        int pos = atomicAdd(&cursor[d], 1);
        csr_src[pos] = s;
        csr_w[pos] = dinv[s];
    }
}

// ===== dense GEMM: C[N][64] = A[N][64] @ W[64][64] (+bias,relu; fp32 or bf16 out) =====
template <bool RELU_BIAS, bool OUT_BF16>
__global__ __launch_bounds__(256) void k_gemm64(const float* __restrict__ A,
                                                const float* __restrict__ W,
                                                const float* __restrict__ bias,
                                                void* __restrict__ Cv, int N) {
    __shared__ __align__(16) float As[64][68];
    __shared__ __align__(16) float Ws[64][68];
    int tid = threadIdx.x;
    int n0 = blockIdx.x * 64;

    #pragma unroll
    for (int p = 0; p < 4; ++p) {
        int flat = p * 1024 + tid * 4;
        int r = flat >> 6, c = flat & 63;
        float4 w = *reinterpret_cast<const float4*>(W + flat);
        *reinterpret_cast<float4*>(&Ws[r][c]) = w;
        int node = n0 + r;
        float4 a = make_float4(0.f, 0.f, 0.f, 0.f);
        if (node < N) a = *reinterpret_cast<const float4*>(A + (size_t)node * 64 + c);
        *reinterpret_cast<float4*>(&As[r][c]) = a;
    }
    __syncthreads();

    int tx = tid & 15;
    int ty = tid >> 4;
    float acc[4][4];
    #pragma unroll
    for (int i = 0; i < 4; ++i)
        #pragma unroll
        for (int j = 0; j < 4; ++j) acc[i][j] = 0.f;

    #pragma unroll
    for (int k4 = 0; k4 < 16; ++k4) {
        float4 a[4], w[4];
        #pragma unroll
        for (int ni = 0; ni < 4; ++ni)
            a[ni] = *reinterpret_cast<const float4*>(&As[ty * 4 + ni][k4 * 4]);
        #pragma unroll
        for (int j = 0; j < 4; ++j)
            w[j] = *reinterpret_cast<const float4*>(&Ws[k4 * 4 + j][tx * 4]);
        #pragma unroll
        for (int ni = 0; ni < 4; ++ni) {
            const float* av = reinterpret_cast<const float*>(&a[ni]);
            #pragma unroll
            for (int j = 0; j < 4; ++j) {
                float ak = av[j];
                acc[ni][0] += ak * w[j].x;
                acc[ni][1] += ak * w[j].y;
                acc[ni][2] += ak * w[j].z;
                acc[ni][3] += ak * w[j].w;
            }
        }
    }

    float4 bv = make_float4(0.f, 0.f, 0.f, 0.f);
    if (RELU_BIAS) bv = *reinterpret_cast<const float4*>(bias + tx * 4);
    #pragma unroll
    for (int ni = 0; ni < 4; ++ni) {
        int node = n0 + ty * 4 + ni;
        if (node < N) {
            float4 c;
            c.x = acc[ni][0]; c.y = acc[ni][1]; c.z = acc[ni][2]; c.w = acc[ni][3];
            if (RELU_BIAS) {
                c.x = fmaxf(c.x + bv.x, 0.f);
                c.y = fmaxf(c.y + bv.y, 0.f);
                c.z = fmaxf(c.z + bv.z, 0.f);
                c.w = fmaxf(c.w + bv.w, 0.f);
            }
            if (OUT_BF16) {
                ushort4 cb;
                cb.x = f2bf(c.x); cb.y = f2bf(c.y); cb.z = f2bf(c.z); cb.w = f2bf(c.w);
                *reinterpret_cast<ushort4*>((u16*)Cv + (size_t)node * 64 + tx * 4) = cb;
            } else {
                *reinterpret_cast<float4*>((float*)Cv + (size_t)node * 64 + tx * 4) = c;
            }
        }
    }
}

// ===== gather (bf16 rows, 4 edges/wave, unroll x2) + bias + relu + LN =====
__global__ __launch_bounds__(256) void k_gather_ln(const u16* __restrict__ Hb,
                                                   const int* __restrict__ row_ptr,
                                                   const int* __restrict__ csr_src,
                                                   const float* __restrict__ csr_w,
                                                   const float* __restrict__ dinv,
                                                   const float* __restrict__ b,
                                                   const float* __restrict__ g,
                                                   const float* __restrict__ beta,
                                                   float* __restrict__ out, int N) {
    int wid = (blockIdx.x * blockDim.x + threadIdx.x) >> 6;
    if (wid >= N) return;
    int lane = threadIdx.x & 63;
    int grp = lane >> 4;   // edge group 0..3
    int fl = lane & 15;    // feature block: features 4*fl .. 4*fl+3
    const ushort4* H4 = reinterpret_cast<const ushort4*>(Hb);

    float ax = 0.f, ay = 0.f, az = 0.f, aw = 0.f;
    int beg = row_ptr[wid], end = row_ptr[wid + 1];
    int j = beg + grp;
    for (; j + 4 < end; j += 8) {
        int s0 = csr_src[j];
        float w0 = csr_w[j];
        int s1 = csr_src[j + 4];
        float w1 = csr_w[j + 4];
        ushort4 h0 = H4[(size_t)s0 * 16 + fl];
        ushort4 h1 = H4[(size_t)s1 * 16 + fl];
        ax += w0 * bf2f(h0.x) + w1 * bf2f(h1.x);
        ay += w0 * bf2f(h0.y) + w1 * bf2f(h1.y);
        az += w0 * bf2f(h0.z) + w1 * bf2f(h1.z);
        aw += w0 * bf2f(h0.w) + w1 * bf2f(h1.w);
    }
    if (j < end) {
        int s0 = csr_src[j];
        float w0 = csr_w[j];
        ushort4 h0 = H4[(size_t)s0 * 16 + fl];
        ax += w0 * bf2f(h0.x);
        ay += w0 * bf2f(h0.y);
        az += w0 * bf2f(h0.z);
        aw += w0 * bf2f(h0.w);
    }
    float dd = dinv[wid];
    if (grp == 0) {   // self loop, weight dd
        ushort4 hs = H4[(size_t)wid * 16 + fl];
        ax += dd * bf2f(hs.x);
        ay += dd * bf2f(hs.y);
        az += dd * bf2f(hs.z);
        aw += dd * bf2f(hs.w);
    }
    // reduce across the 4 edge groups (lanes with equal fl)
    ax += __shfl_xor(ax, 16); ax += __shfl_xor(ax, 32);
    ay += __shfl_xor(ay, 16); ay += __shfl_xor(ay, 32);
    az += __shfl_xor(az, 16); az += __shfl_xor(az, 32);
    aw += __shfl_xor(aw, 16); aw += __shfl_xor(aw, 32);
    ax *= dd; ay *= dd; az *= dd; aw *= dd;

    float4 bv = *reinterpret_cast<const float4*>(b + fl * 4);
    float vx = fmaxf(ax + bv.x, 0.f);
    float vy = fmaxf(ay + bv.y, 0.f);
    float vz = fmaxf(az + bv.z, 0.f);
    float vw = fmaxf(aw + bv.w, 0.f);

    float s = vx + vy + vz + vw;
    #pragma unroll
    for (int off = 1; off < 16; off <<= 1) s += __shfl_xor(s, off);
    float mu = s * (1.0f / 64.0f);
    float dx = vx - mu, dy = vy - mu, dz = vz - mu, dw = vw - mu;
    float vs = dx * dx + dy * dy + dz * dz + dw * dw;
    #pragma unroll
    for (int off = 1; off < 16; off <<= 1) vs += __shfl_xor(vs, off);
    float r = rsqrtf(vs * (1.0f / 64.0f) + LN_EPS);

    if (grp == 0) {
        float4 gv = *reinterpret_cast<const float4*>(g + fl * 4);
        float4 be = *reinterpret_cast<const float4*>(beta + fl * 4);
        float4 o;
        o.x = dx * r * gv.x + be.x;
        o.y = dy * r * gv.y + be.y;
        o.z = dz * r * gv.z + be.z;
        o.w = dw * r * gv.w + be.w;
        *reinterpret_cast<float4*>(out + (size_t)wid * 64 + fl * 4) = o;
    }
}

// ================= final: out[N][3] = H[N][64] @ Wm2[64][3] + bm2 =================
__global__ void k_mlp_out(const float* __restrict__ H, const float* __restrict__ Wm2,
                          const float* __restrict__ bm2, float* __restrict__ out, int N) {
    __shared__ float Ws[192];
    __shared__ float bs[3];
    if (threadIdx.x < 192) Ws[threadIdx.x] = Wm2[threadIdx.x];
    if (threadIdx.x < 3) bs[threadIdx.x] = bm2[threadIdx.x];
    __syncthreads();
    int i = blockIdx.x * blockDim.x + threadIdx.x;
    if (i >= N) return;
    float a0 = 0.f, a1 = 0.f, a2 = 0.f;
    const float4* h4 = reinterpret_cast<const float4*>(H + (size_t)i * 64);
    #pragma unroll
    for (int q = 0; q < 16; ++q) {
        float4 h = h4[q];
        float hv[4] = {h.x, h.y, h.z, h.w};
        #pragma unroll
        for (int j = 0; j < 4; ++j) {
            int k = q * 4 + j;
            a0 += hv[j] * Ws[k * 3 + 0];
            a1 += hv[j] * Ws[k * 3 + 1];
            a2 += hv[j] * Ws[k * 3 + 2];
        }
    }
    out[(size_t)i * 3 + 0] = a0 + bs[0];
    out[(size_t)i * 3 + 1] = a1 + bs[1];
    out[(size_t)i * 3 + 2] = a2 + bs[2];
}

extern "C" void kernel_launch(void* const* d_in, const int* in_sizes, int n_in,
                              void* d_out, int out_size, void* d_ws, size_t ws_size,
                              hipStream_t stream) {
    const float* z     = (const float*)d_in[0];
    const int*   ei    = (const int*)d_in[1];
    const float* W1    = (const float*)d_in[2];
    const float* b1    = (const float*)d_in[3];
    const float* g1    = (const float*)d_in[4];
    const float* beta1 = (const float*)d_in[5];
    const float* W2    = (const float*)d_in[6];
    const float* b2    = (const float*)d_in[7];
    const float* g2    = (const float*)d_in[8];
    const float* beta2 = (const float*)d_in[9];
    const float* Wm1   = (const float*)d_in[10];
    const float* bm1   = (const float*)d_in[11];
    const float* Wm2   = (const float*)d_in[12];
    const float* bm2   = (const float*)d_in[13];

    int N = in_sizes[0] / 64;
    int E = in_sizes[1] / 2;
    const int* src = ei;
    const int* dst = ei + E;
    float* out = (float*)d_out;

    size_t Nr = ((size_t)N + 1023) & ~(size_t)1023;
    size_t Er = ((size_t)E + 3) & ~(size_t)3;
    size_t N64 = (size_t)N * 64;
    int*   cnt     = (int*)d_ws;
    int*   row_ptr = cnt + Nr;
    int*   cursor  = row_ptr + Nr;
    int*   bsum    = cursor + Nr;       // 1024
    float* dinv    = (float*)(bsum + 1024);
    int*   csr_src = (int*)(dinv + Nr);
    float* csr_w   = (float*)(csr_src + Er);
    u16*   Hb      = (u16*)(csr_w + Er);            // N*64 bf16
    float* B3      = (float*)(Hb + ((N64 + 1) & ~(size_t)1)); // N*64 fp32
    float* B1      = B3 + N64;                      // N*64 fp32

    int nb_n = (N + 255) / 256;
    int nb_g = (N + 63) / 64;
    int nb_c = (N + 1023) / 1024;
    int nb_w = (N * 64 + 255) / 256;

    // ---- CSR build ----
    k_zero<<<nb_n, 256, 0, stream>>>(cnt, N);
    k_count<<<1024, 256, 0, stream>>>(dst, cnt, E);
    k_blocksum<<<nb_c, 256, 0, stream>>>(cnt, bsum, N);
    k_scan_bsums<<<1, 256, 0, stream>>>(bsum, nb_c, row_ptr, N);
    k_scan_chunk<<<nb_c, 256, 0, stream>>>(cnt, bsum, row_ptr, cursor, dinv, N);
    k_fill<<<1024, 256, 0, stream>>>(src, dst, dinv, cursor, csr_src, csr_w, E);

    // ---- layer 1 ----
    k_gemm64<false, true><<<nb_g, 256, 0, stream>>>(z, W1, nullptr, Hb, N);
    k_gather_ln<<<nb_w, 256, 0, stream>>>(Hb, row_ptr, csr_src, csr_w, dinv,
                                          b1, g1, beta1, B3, N);
    // ---- layer 2 ----
    k_gemm64<false, true><<<nb_g, 256, 0, stream>>>(B3, W2, nullptr, Hb, N);
    k_gather_ln<<<nb_w, 256, 0, stream>>>(Hb, row_ptr, csr_src, csr_w, dinv,
                                          b2, g2, beta2, B3, N);
    // ---- MLP head ----
    k_gemm64<true, false><<<nb_g, 256, 0, stream>>>(B3, Wm1, bm1, B1, N);
    k_mlp_out<<<nb_n, 256, 0, stream>>>(B1, Wm2, bm2, out, N);
}

// Round 4
// 300.644 us; speedup vs baseline: 3.1867x; 1.4161x over previous
//
#include <hip/hip_runtime.h>
#include <hip/hip_bf16.h>

#define LN_EPS 1e-5f
#define EPB 4096          // edges per block in bucket passes
typedef unsigned short u16;

static __device__ __forceinline__ float bf2f(u16 x) {
    return __uint_as_float(((unsigned int)x) << 16);
}
static __device__ __forceinline__ u16 f2bf(float f) {
    unsigned int u = __float_as_uint(f);
    return (u16)((u + 0x7fff + ((u >> 16) & 1)) >> 16);  // RNE
}

// ================= CSR build: two-level counting sort (bucket = dst>>8) =================
// p1: per-block bucket histogram -> blockhist[b][k]  (no global atomics)
__global__ __launch_bounds__(256) void k_p1_hist(const int* __restrict__ dst,
                                                 int* __restrict__ blockhist,
                                                 int E, int NB) {
    extern __shared__ int h[];
    int b = blockIdx.x, t = threadIdx.x;
    for (int j = t; j < NB; j += 256) h[j] = 0;
    __syncthreads();
    int e0 = b * EPB, e1 = min(E, e0 + EPB);
    for (int e = e0 + t; e < e1; e += 256)
        atomicAdd(&h[dst[e] >> 8], 1);
    __syncthreads();
    for (int j = t; j < NB; j += 256)
        blockhist[(size_t)b * NB + j] = h[j];
}

// p2a: for each bucket k, exclusive-scan blockhist[:,k] along blocks; emit total
__global__ __launch_bounds__(512) void k_p2a(int* __restrict__ blockhist,
                                             int* __restrict__ btot, int NB, int NB1) {
    __shared__ int sd[512];
    int k = blockIdx.x, t = threadIdx.x;
    int v = (t < NB1) ? blockhist[(size_t)t * NB + k] : 0;
    sd[t] = v;
    __syncthreads();
    for (int off = 1; off < 512; off <<= 1) {
        int x = (t >= off) ? sd[t - off] : 0;
        __syncthreads();
        sd[t] += x;
        __syncthreads();
    }
    if (t < NB1) blockhist[(size_t)t * NB + k] = sd[t] - v;
    if (t == 511) btot[k] = sd[511];
}

// p2b: exclusive-scan bucket totals -> bbase (NB+1 entries); row_ptr[N]=E
__global__ __launch_bounds__(512) void k_p2b(const int* __restrict__ btot,
                                             int* __restrict__ bbase,
                                             int* __restrict__ row_ptr,
                                             int NB, int N, int E) {
    __shared__ int sd[512];
    int t = threadIdx.x;
    int v = (t < NB) ? btot[t] : 0;
    sd[t] = v;
    __syncthreads();
    for (int off = 1; off < 512; off <<= 1) {
        int x = (t >= off) ? sd[t - off] : 0;
        __syncthreads();
        sd[t] += x;
        __syncthreads();
    }
    if (t < NB) bbase[t] = sd[t] - v;
    if (t == 0) { bbase[NB] = E; row_ptr[N] = E; }
}

// p3: scatter packed entries (src<<8 | dst_local) into bucket-sorted order
__global__ __launch_bounds__(256) void k_p3_scatter(const int* __restrict__ src,
                                                    const int* __restrict__ dst,
                                                    const int* __restrict__ blockhist,
                                                    const int* __restrict__ bbase,
                                                    int* __restrict__ entries,
                                                    int E, int NB) {
    extern __shared__ int cur[];
    int b = blockIdx.x, t = threadIdx.x;
    for (int j = t; j < NB; j += 256)
        cur[j] = bbase[j] + blockhist[(size_t)b * NB + j];
    __syncthreads();
    int e0 = b * EPB, e1 = min(E, e0 + EPB);
    for (int e = e0 + t; e < e1; e += 256) {
        int d = dst[e];
        int p = atomicAdd(&cur[d >> 8], 1);
        entries[p] = (src[e] << 8) | (d & 255);
    }
}

// p4: per-bucket: node histogram -> row_ptr, dinv; place csr_src (coalesced window)
__global__ __launch_bounds__(256) void k_p4_csr(const int* __restrict__ entries,
                                                const int* __restrict__ bbase,
                                                int* __restrict__ row_ptr,
                                                float* __restrict__ dinv,
                                                int* __restrict__ csr_src, int N) {
    __shared__ int hist[256];
    __shared__ int sd[256];
    __shared__ int cur[256];
    int k = blockIdx.x, t = threadIdx.x;
    int b0 = bbase[k], b1 = bbase[k + 1];
    hist[t] = 0;
    __syncthreads();
    for (int e = b0 + t; e < b1; e += 256)
        atomicAdd(&hist[entries[e] & 255], 1);
    __syncthreads();
    int v = hist[t];
    sd[t] = v;
    __syncthreads();
    for (int off = 1; off < 256; off <<= 1) {
        int x = (t >= off) ? sd[t - off] : 0;
        __syncthreads();
        sd[t] += x;
        __syncthreads();
    }
    int excl = sd[t] - v;
    int node = (k << 8) + t;
    if (node < N) {
        row_ptr[node] = b0 + excl;
        dinv[node] = rsqrtf(1.0f + (float)v);
    }
    cur[t] = b0 + excl;
    __syncthreads();
    for (int e = b0 + t; e < b1; e += 256) {
        int en = entries[e];
        int p = atomicAdd(&cur[en & 255], 1);
        csr_src[p] = en >> 8;
    }
}

// ===== dense GEMM: C[N][64] = A[N][64] @ W[64][64] (+bias,relu; fp32 or bf16 out) =====
template <bool RELU_BIAS, bool OUT_BF16>
__global__ __launch_bounds__(256) void k_gemm64(const float* __restrict__ A,
                                                const float* __restrict__ W,
                                                const float* __restrict__ bias,
                                                void* __restrict__ Cv, int N) {
    __shared__ __align__(16) float As[64][68];
    __shared__ __align__(16) float Ws[64][68];
    int tid = threadIdx.x;
    int n0 = blockIdx.x * 64;

    #pragma unroll
    for (int p = 0; p < 4; ++p) {
        int flat = p * 1024 + tid * 4;
        int r = flat >> 6, c = flat & 63;
        float4 w = *reinterpret_cast<const float4*>(W + flat);
        *reinterpret_cast<float4*>(&Ws[r][c]) = w;
        int node = n0 + r;
        float4 a = make_float4(0.f, 0.f, 0.f, 0.f);
        if (node < N) a = *reinterpret_cast<const float4*>(A + (size_t)node * 64 + c);
        *reinterpret_cast<float4*>(&As[r][c]) = a;
    }
    __syncthreads();

    int tx = tid & 15;
    int ty = tid >> 4;
    float acc[4][4];
    #pragma unroll
    for (int i = 0; i < 4; ++i)
        #pragma unroll
        for (int j = 0; j < 4; ++j) acc[i][j] = 0.f;

    #pragma unroll
    for (int k4 = 0; k4 < 16; ++k4) {
        float4 a[4], w[4];
        #pragma unroll
        for (int ni = 0; ni < 4; ++ni)
            a[ni] = *reinterpret_cast<const float4*>(&As[ty * 4 + ni][k4 * 4]);
        #pragma unroll
        for (int j = 0; j < 4; ++j)
            w[j] = *reinterpret_cast<const float4*>(&Ws[k4 * 4 + j][tx * 4]);
        #pragma unroll
        for (int ni = 0; ni < 4; ++ni) {
            const float* av = reinterpret_cast<const float*>(&a[ni]);
            #pragma unroll
            for (int j = 0; j < 4; ++j) {
                float ak = av[j];
                acc[ni][0] += ak * w[j].x;
                acc[ni][1] += ak * w[j].y;
                acc[ni][2] += ak * w[j].z;
                acc[ni][3] += ak * w[j].w;
            }
        }
    }

    float4 bv = make_float4(0.f, 0.f, 0.f, 0.f);
    if (RELU_BIAS) bv = *reinterpret_cast<const float4*>(bias + tx * 4);
    #pragma unroll
    for (int ni = 0; ni < 4; ++ni) {
        int node = n0 + ty * 4 + ni;
        if (node < N) {
            float4 c;
            c.x = acc[ni][0]; c.y = acc[ni][1]; c.z = acc[ni][2]; c.w = acc[ni][3];
            if (RELU_BIAS) {
                c.x = fmaxf(c.x + bv.x, 0.f);
                c.y = fmaxf(c.y + bv.y, 0.f);
                c.z = fmaxf(c.z + bv.z, 0.f);
                c.w = fmaxf(c.w + bv.w, 0.f);
            }
            if (OUT_BF16) {
                ushort4 cb;
                cb.x = f2bf(c.x); cb.y = f2bf(c.y); cb.z = f2bf(c.z); cb.w = f2bf(c.w);
                *reinterpret_cast<ushort4*>((u16*)Cv + (size_t)node * 64 + tx * 4) = cb;
            } else {
                *reinterpret_cast<float4*>((float*)Cv + (size_t)node * 64 + tx * 4) = c;
            }
        }
    }
}

// ===== gather (bf16 rows, 4 edges/wave, unroll x2) + bias + relu + LN =====
__global__ __launch_bounds__(256) void k_gather_ln(const u16* __restrict__ Hb,
                                                   const int* __restrict__ row_ptr,
                                                   const int* __restrict__ csr_src,
                                                   const float* __restrict__ dinv,
                                                   const float* __restrict__ b,
                                                   const float* __restrict__ g,
                                                   const float* __restrict__ beta,
                                                   float* __restrict__ out, int N) {
    int wid = (blockIdx.x * blockDim.x + threadIdx.x) >> 6;
    if (wid >= N) return;
    int lane = threadIdx.x & 63;
    int grp = lane >> 4;   // edge group 0..3
    int fl = lane & 15;    // feature block: features 4*fl .. 4*fl+3
    const ushort4* H4 = reinterpret_cast<const ushort4*>(Hb);

    float ax = 0.f, ay = 0.f, az = 0.f, aw = 0.f;
    int beg = row_ptr[wid], end = row_ptr[wid + 1];
    int j = beg + grp;
    for (; j + 4 < end; j += 8) {
        int s0 = csr_src[j];
        int s1 = csr_src[j + 4];
        float w0 = dinv[s0];
        float w1 = dinv[s1];
        ushort4 h0 = H4[(size_t)s0 * 16 + fl];
        ushort4 h1 = H4[(size_t)s1 * 16 + fl];
        ax += w0 * bf2f(h0.x) + w1 * bf2f(h1.x);
        ay += w0 * bf2f(h0.y) + w1 * bf2f(h1.y);
        az += w0 * bf2f(h0.z) + w1 * bf2f(h1.z);
        aw += w0 * bf2f(h0.w) + w1 * bf2f(h1.w);
    }
    if (j < end) {
        int s0 = csr_src[j];
        float w0 = dinv[s0];
        ushort4 h0 = H4[(size_t)s0 * 16 + fl];
        ax += w0 * bf2f(h0.x);
        ay += w0 * bf2f(h0.y);
        az += w0 * bf2f(h0.z);
        aw += w0 * bf2f(h0.w);
    }
    float dd = dinv[wid];
    if (grp == 0) {   // self loop, weight dd
        ushort4 hs = H4[(size_t)wid * 16 + fl];
        ax += dd * bf2f(hs.x);
        ay += dd * bf2f(hs.y);
        az += dd * bf2f(hs.z);
        aw += dd * bf2f(hs.w);
    }
    ax += __shfl_xor(ax, 16); ax += __shfl_xor(ax, 32);
    ay += __shfl_xor(ay, 16); ay += __shfl_xor(ay, 32);
    az += __shfl_xor(az, 16); az += __shfl_xor(az, 32);
    aw += __shfl_xor(aw, 16); aw += __shfl_xor(aw, 32);
    ax *= dd; ay *= dd; az *= dd; aw *= dd;

    float4 bv = *reinterpret_cast<const float4*>(b + fl * 4);
    float vx = fmaxf(ax + bv.x, 0.f);
    float vy = fmaxf(ay + bv.y, 0.f);
    float vz = fmaxf(az + bv.z, 0.f);
    float vw = fmaxf(aw + bv.w, 0.f);

    float s = vx + vy + vz + vw;
    #pragma unroll
    for (int off = 1; off < 16; off <<= 1) s += __shfl_xor(s, off);
    float mu = s * (1.0f / 64.0f);
    float dx = vx - mu, dy = vy - mu, dz = vz - mu, dw = vw - mu;
    float vs = dx * dx + dy * dy + dz * dz + dw * dw;
    #pragma unroll
    for (int off = 1; off < 16; off <<= 1) vs += __shfl_xor(vs, off);
    float r = rsqrtf(vs * (1.0f / 64.0f) + LN_EPS);

    if (grp == 0) {
        float4 gv = *reinterpret_cast<const float4*>(g + fl * 4);
        float4 be = *reinterpret_cast<const float4*>(beta + fl * 4);
        float4 o;
        o.x = dx * r * gv.x + be.x;
        o.y = dy * r * gv.y + be.y;
        o.z = dz * r * gv.z + be.z;
        o.w = dw * r * gv.w + be.w;
        *reinterpret_cast<float4*>(out + (size_t)wid * 64 + fl * 4) = o;
    }
}

// ================= final: out[N][3] = H[N][64] @ Wm2[64][3] + bm2 =================
__global__ void k_mlp_out(const float* __restrict__ H, const float* __restrict__ Wm2,
                          const float* __restrict__ bm2, float* __restrict__ out, int N) {
    __shared__ float Ws[192];
    __shared__ float bs[3];
    if (threadIdx.x < 192) Ws[threadIdx.x] = Wm2[threadIdx.x];
    if (threadIdx.x < 3) bs[threadIdx.x] = bm2[threadIdx.x];
    __syncthreads();
    int i = blockIdx.x * blockDim.x + threadIdx.x;
    if (i >= N) return;
    float a0 = 0.f, a1 = 0.f, a2 = 0.f;
    const float4* h4 = reinterpret_cast<const float4*>(H + (size_t)i * 64);
    #pragma unroll
    for (int q = 0; q < 16; ++q) {
        float4 h = h4[q];
        float hv[4] = {h.x, h.y, h.z, h.w};
        #pragma unroll
        for (int j = 0; j < 4; ++j) {
            int k = q * 4 + j;
            a0 += hv[j] * Ws[k * 3 + 0];
            a1 += hv[j] * Ws[k * 3 + 1];
            a2 += hv[j] * Ws[k * 3 + 2];
        }
    }
    out[(size_t)i * 3 + 0] = a0 + bs[0];
    out[(size_t)i * 3 + 1] = a1 + bs[1];
    out[(size_t)i * 3 + 2] = a2 + bs[2];
}

extern "C" void kernel_launch(void* const* d_in, const int* in_sizes, int n_in,
                              void* d_out, int out_size, void* d_ws, size_t ws_size,
                              hipStream_t stream) {
    const float* z     = (const float*)d_in[0];
    const int*   ei    = (const int*)d_in[1];
    const float* W1    = (const float*)d_in[2];
    const float* b1    = (const float*)d_in[3];
    const float* g1    = (const float*)d_in[4];
    const float* beta1 = (const float*)d_in[5];
    const float* W2    = (const float*)d_in[6];
    const float* b2    = (const float*)d_in[7];
    const float* g2    = (const float*)d_in[8];
    const float* beta2 = (const float*)d_in[9];
    const float* Wm1   = (const float*)d_in[10];
    const float* bm1   = (const float*)d_in[11];
    const float* Wm2   = (const float*)d_in[12];
    const float* bm2   = (const float*)d_in[13];

    int N = in_sizes[0] / 64;
    int E = in_sizes[1] / 2;
    const int* src = ei;
    const int* dst = ei + E;
    float* out = (float*)d_out;

    int NB  = (N + 255) >> 8;          // buckets (dst>>8)
    int NB1 = (E + EPB - 1) / EPB;     // edge blocks

    // workspace layout
    size_t N64 = (size_t)N * 64;
    auto rnd = [](size_t x) { return (x + 1023) & ~(size_t)1023; };
    int*   bbase     = (int*)d_ws;                       // NB+1
    int*   btot      = bbase + rnd(NB + 1);              // NB
    int*   blockhist = btot + rnd(NB);                   // NB1*NB
    int*   entries   = blockhist + rnd((size_t)NB1 * NB);// E
    int*   row_ptr   = entries + rnd(E);                 // N+1
    float* dinv      = (float*)(row_ptr + rnd(N + 1));   // N
    int*   csr_src   = (int*)(dinv + rnd(N));            // E
    u16*   Hb        = (u16*)(csr_src + rnd(E));         // N*64 bf16
    float* B3        = (float*)(Hb + rnd(N64));          // N*64 fp32
    float* B1        = B3 + N64;                         // N*64 fp32

    int nb_n = (N + 255) / 256;
    int nb_g = (N + 63) / 64;
    int nb_w = (N * 64 + 255) / 256;
    size_t lds_nb = (size_t)NB * sizeof(int);

    // ---- CSR build (two-level counting sort) ----
    k_p1_hist<<<NB1, 256, lds_nb, stream>>>(dst, blockhist, E, NB);
    k_p2a<<<NB, 512, 0, stream>>>(blockhist, btot, NB, NB1);
    k_p2b<<<1, 512, 0, stream>>>(btot, bbase, row_ptr, NB, N, E);
    k_p3_scatter<<<NB1, 256, lds_nb, stream>>>(src, dst, blockhist, bbase, entries, E, NB);
    k_p4_csr<<<NB, 256, 0, stream>>>(entries, bbase, row_ptr, dinv, csr_src, N);

    // ---- layer 1 ----
    k_gemm64<false, true><<<nb_g, 256, 0, stream>>>(z, W1, nullptr, Hb, N);
    k_gather_ln<<<nb_w, 256, 0, stream>>>(Hb, row_ptr, csr_src, dinv, b1, g1, beta1, B3, N);
    // ---- layer 2 ----
    k_gemm64<false, true><<<nb_g, 256, 0, stream>>>(B3, W2, nullptr, Hb, N);
    k_gather_ln<<<nb_w, 256, 0, stream>>>(Hb, row_ptr, csr_src, dinv, b2, g2, beta2, B3, N);
    // ---- MLP head ----
    k_gemm64<true, false><<<nb_g, 256, 0, stream>>>(B3, Wm1, bm1, B1, N);
    k_mlp_out<<<nb_n, 256, 0, stream>>>(B1, Wm2, bm2, out, N);
}

// Round 5
// 256.007 us; speedup vs baseline: 3.7423x; 1.1744x over previous
//
#include <hip/hip_runtime.h>
#include <hip/hip_bf16.h>

#define LN_EPS 1e-5f
#define EPB 4096          // edges per block in bucket passes
typedef unsigned short u16;
typedef unsigned short us8 __attribute__((ext_vector_type(8)));

static __device__ __forceinline__ float bf2f(u16 x) {
    return __uint_as_float(((unsigned int)x) << 16);
}
static __device__ __forceinline__ u16 f2bf(float f) {
    unsigned int u = __float_as_uint(f);
    return (u16)((u + 0x7fff + ((u >> 16) & 1)) >> 16);  // RNE
}

// ================= CSR build: two-level counting sort (bucket = dst>>8) =================
__global__ __launch_bounds__(256) void k_p1_hist(const int* __restrict__ dst,
                                                 int* __restrict__ blockhist,
                                                 int E, int NB) {
    extern __shared__ int h[];
    int b = blockIdx.x, t = threadIdx.x;
    for (int j = t; j < NB; j += 256) h[j] = 0;
    __syncthreads();
    int e0 = b * EPB, e1 = min(E, e0 + EPB);
    for (int e = e0 + t; e < e1; e += 256)
        atomicAdd(&h[dst[e] >> 8], 1);
    __syncthreads();
    for (int j = t; j < NB; j += 256)
        blockhist[(size_t)b * NB + j] = h[j];
}

__global__ __launch_bounds__(512) void k_p2a(int* __restrict__ blockhist,
                                             int* __restrict__ btot, int NB, int NB1) {
    __shared__ int sd[512];
    int k = blockIdx.x, t = threadIdx.x;
    int v = (t < NB1) ? blockhist[(size_t)t * NB + k] : 0;
    sd[t] = v;
    __syncthreads();
    for (int off = 1; off < 512; off <<= 1) {
        int x = (t >= off) ? sd[t - off] : 0;
        __syncthreads();
        sd[t] += x;
        __syncthreads();
    }
    if (t < NB1) blockhist[(size_t)t * NB + k] = sd[t] - v;
    if (t == 511) btot[k] = sd[511];
}

__global__ __launch_bounds__(512) void k_p2b(const int* __restrict__ btot,
                                             int* __restrict__ bbase,
                                             int* __restrict__ row_ptr,
                                             int NB, int N, int E) {
    __shared__ int sd[512];
    int t = threadIdx.x;
    int v = (t < NB) ? btot[t] : 0;
    sd[t] = v;
    __syncthreads();
    for (int off = 1; off < 512; off <<= 1) {
        int x = (t >= off) ? sd[t - off] : 0;
        __syncthreads();
        sd[t] += x;
        __syncthreads();
    }
    if (t < NB) bbase[t] = sd[t] - v;
    if (t == 0) { bbase[NB] = E; row_ptr[N] = E; }
}

__global__ __launch_bounds__(256) void k_p3_scatter(const int* __restrict__ src,
                                                    const int* __restrict__ dst,
                                                    const int* __restrict__ blockhist,
                                                    const int* __restrict__ bbase,
                                                    int* __restrict__ entries,
                                                    int E, int NB) {
    extern __shared__ int cur[];
    int b = blockIdx.x, t = threadIdx.x;
    for (int j = t; j < NB; j += 256)
        cur[j] = bbase[j] + blockhist[(size_t)b * NB + j];
    __syncthreads();
    int e0 = b * EPB, e1 = min(E, e0 + EPB);
    for (int e = e0 + t; e < e1; e += 256) {
        int d = dst[e];
        int p = atomicAdd(&cur[d >> 8], 1);
        entries[p] = (src[e] << 8) | (d & 255);
    }
}

__global__ __launch_bounds__(256) void k_p4_csr(const int* __restrict__ entries,
                                                const int* __restrict__ bbase,
                                                int* __restrict__ row_ptr,
                                                float* __restrict__ dinv,
                                                int* __restrict__ csr_src, int N) {
    __shared__ int hist[256];
    __shared__ int sd[256];
    __shared__ int cur[256];
    int k = blockIdx.x, t = threadIdx.x;
    int b0 = bbase[k], b1 = bbase[k + 1];
    hist[t] = 0;
    __syncthreads();
    for (int e = b0 + t; e < b1; e += 256)
        atomicAdd(&hist[entries[e] & 255], 1);
    __syncthreads();
    int v = hist[t];
    sd[t] = v;
    __syncthreads();
    for (int off = 1; off < 256; off <<= 1) {
        int x = (t >= off) ? sd[t - off] : 0;
        __syncthreads();
        sd[t] += x;
        __syncthreads();
    }
    int excl = sd[t] - v;
    int node = (k << 8) + t;
    if (node < N) {
        row_ptr[node] = b0 + excl;
        dinv[node] = rsqrtf(1.0f + (float)v);
    }
    cur[t] = b0 + excl;
    __syncthreads();
    for (int e = b0 + t; e < b1; e += 256) {
        int en = entries[e];
        int p = atomicAdd(&cur[en & 255], 1);
        csr_src[p] = en >> 8;
    }
}

// ===== dense GEMM: C[N][64] = A[N][64] @ W[64][64] (bf16 out) =====
__global__ __launch_bounds__(256) void k_gemm64_bf16(const float* __restrict__ A,
                                                     const float* __restrict__ W,
                                                     u16* __restrict__ C, int N) {
    __shared__ __align__(16) float As[64][68];
    __shared__ __align__(16) float Ws[64][68];
    int tid = threadIdx.x;
    int n0 = blockIdx.x * 64;

    #pragma unroll
    for (int p = 0; p < 4; ++p) {
        int flat = p * 1024 + tid * 4;
        int r = flat >> 6, c = flat & 63;
        float4 w = *reinterpret_cast<const float4*>(W + flat);
        *reinterpret_cast<float4*>(&Ws[r][c]) = w;
        int node = n0 + r;
        float4 a = make_float4(0.f, 0.f, 0.f, 0.f);
        if (node < N) a = *reinterpret_cast<const float4*>(A + (size_t)node * 64 + c);
        *reinterpret_cast<float4*>(&As[r][c]) = a;
    }
    __syncthreads();

    int tx = tid & 15;
    int ty = tid >> 4;
    float acc[4][4];
    #pragma unroll
    for (int i = 0; i < 4; ++i)
        #pragma unroll
        for (int j = 0; j < 4; ++j) acc[i][j] = 0.f;

    #pragma unroll
    for (int k4 = 0; k4 < 16; ++k4) {
        float4 a[4], w[4];
        #pragma unroll
        for (int ni = 0; ni < 4; ++ni)
            a[ni] = *reinterpret_cast<const float4*>(&As[ty * 4 + ni][k4 * 4]);
        #pragma unroll
        for (int j = 0; j < 4; ++j)
            w[j] = *reinterpret_cast<const float4*>(&Ws[k4 * 4 + j][tx * 4]);
        #pragma unroll
        for (int ni = 0; ni < 4; ++ni) {
            const float* av = reinterpret_cast<const float*>(&a[ni]);
            #pragma unroll
            for (int j = 0; j < 4; ++j) {
                float ak = av[j];
                acc[ni][0] += ak * w[j].x;
                acc[ni][1] += ak * w[j].y;
                acc[ni][2] += ak * w[j].z;
                acc[ni][3] += ak * w[j].w;
            }
        }
    }

    #pragma unroll
    for (int ni = 0; ni < 4; ++ni) {
        int node = n0 + ty * 4 + ni;
        if (node < N) {
            ushort4 cb;
            cb.x = f2bf(acc[ni][0]); cb.y = f2bf(acc[ni][1]);
            cb.z = f2bf(acc[ni][2]); cb.w = f2bf(acc[ni][3]);
            *reinterpret_cast<ushort4*>(C + (size_t)node * 64 + tx * 4) = cb;
        }
    }
}

// ===== fused MLP head: out[N][3] = relu(A @ Wm1 + bm1) @ Wm2 + bm2 =====
__global__ __launch_bounds__(256) void k_gemm_mlp(const float* __restrict__ A,
                                                  const float* __restrict__ W,
                                                  const float* __restrict__ bias,
                                                  const float* __restrict__ Wm2,
                                                  const float* __restrict__ bm2,
                                                  float* __restrict__ out, int N) {
    __shared__ __align__(16) float As[64][68];
    __shared__ __align__(16) float Ws[64][68];
    int tid = threadIdx.x;
    int n0 = blockIdx.x * 64;

    #pragma unroll
    for (int p = 0; p < 4; ++p) {
        int flat = p * 1024 + tid * 4;
        int r = flat >> 6, c = flat & 63;
        float4 w = *reinterpret_cast<const float4*>(W + flat);
        *reinterpret_cast<float4*>(&Ws[r][c]) = w;
        int node = n0 + r;
        float4 a = make_float4(0.f, 0.f, 0.f, 0.f);
        if (node < N) a = *reinterpret_cast<const float4*>(A + (size_t)node * 64 + c);
        *reinterpret_cast<float4*>(&As[r][c]) = a;
    }
    __syncthreads();

    int tx = tid & 15;
    int ty = tid >> 4;
    float acc[4][4];
    #pragma unroll
    for (int i = 0; i < 4; ++i)
        #pragma unroll
        for (int j = 0; j < 4; ++j) acc[i][j] = 0.f;

    #pragma unroll
    for (int k4 = 0; k4 < 16; ++k4) {
        float4 a[4], w[4];
        #pragma unroll
        for (int ni = 0; ni < 4; ++ni)
            a[ni] = *reinterpret_cast<const float4*>(&As[ty * 4 + ni][k4 * 4]);
        #pragma unroll
        for (int j = 0; j < 4; ++j)
            w[j] = *reinterpret_cast<const float4*>(&Ws[k4 * 4 + j][tx * 4]);
        #pragma unroll
        for (int ni = 0; ni < 4; ++ni) {
            const float* av = reinterpret_cast<const float*>(&a[ni]);
            #pragma unroll
            for (int j = 0; j < 4; ++j) {
                float ak = av[j];
                acc[ni][0] += ak * w[j].x;
                acc[ni][1] += ak * w[j].y;
                acc[ni][2] += ak * w[j].z;
                acc[ni][3] += ak * w[j].w;
            }
        }
    }

    // bias + relu
    float4 bv = *reinterpret_cast<const float4*>(bias + tx * 4);
    #pragma unroll
    for (int ni = 0; ni < 4; ++ni) {
        acc[ni][0] = fmaxf(acc[ni][0] + bv.x, 0.f);
        acc[ni][1] = fmaxf(acc[ni][1] + bv.y, 0.f);
        acc[ni][2] = fmaxf(acc[ni][2] + bv.z, 0.f);
        acc[ni][3] = fmaxf(acc[ni][3] + bv.w, 0.f);
    }

    // per-thread partial of 64x3 projection (features tx*4..tx*4+3)
    float wm[4][3];
    #pragma unroll
    for (int j = 0; j < 4; ++j)
        #pragma unroll
        for (int c = 0; c < 3; ++c)
            wm[j][c] = Wm2[(tx * 4 + j) * 3 + c];
    float p[4][3];
    #pragma unroll
    for (int ni = 0; ni < 4; ++ni) {
        #pragma unroll
        for (int c = 0; c < 3; ++c) {
            p[ni][c] = acc[ni][0] * wm[0][c] + acc[ni][1] * wm[1][c] +
                       acc[ni][2] * wm[2][c] + acc[ni][3] * wm[3][c];
        }
    }
    // reduce across the 16 threads (same ty) — lanes differ only in tx bits
    #pragma unroll
    for (int off = 1; off < 16; off <<= 1)
        #pragma unroll
        for (int ni = 0; ni < 4; ++ni)
            #pragma unroll
            for (int c = 0; c < 3; ++c)
                p[ni][c] += __shfl_xor(p[ni][c], off);
    if (tx == 0) {
        #pragma unroll
        for (int ni = 0; ni < 4; ++ni) {
            int node = n0 + ty * 4 + ni;
            if (node < N) {
                out[(size_t)node * 3 + 0] = p[ni][0] + bm2[0];
                out[(size_t)node * 3 + 1] = p[ni][1] + bm2[1];
                out[(size_t)node * 3 + 2] = p[ni][2] + bm2[2];
            }
        }
    }
}

// ===== gather (bf16 rows, 8 edges/wave, unroll x2) + bias + relu + LN =====
__global__ __launch_bounds__(256) void k_gather_ln(const u16* __restrict__ Hb,
                                                   const int* __restrict__ row_ptr,
                                                   const int* __restrict__ csr_src,
                                                   const float* __restrict__ dinv,
                                                   const float* __restrict__ b,
                                                   const float* __restrict__ g,
                                                   const float* __restrict__ beta,
                                                   float* __restrict__ out, int N) {
    int wid = (blockIdx.x * blockDim.x + threadIdx.x) >> 6;
    if (wid >= N) return;
    int lane = threadIdx.x & 63;
    int grp = lane >> 3;   // edge group 0..7
    int fl = lane & 7;     // feature octet: features 8*fl .. 8*fl+7
    const us8* H8 = reinterpret_cast<const us8*>(Hb);

    float a[8];
    #pragma unroll
    for (int k = 0; k < 8; ++k) a[k] = 0.f;

    int beg = row_ptr[wid], end = row_ptr[wid + 1];
    int j = beg + grp;
    for (; j + 8 < end; j += 16) {
        int s0 = csr_src[j];
        int s1 = csr_src[j + 8];
        float w0 = dinv[s0];
        float w1 = dinv[s1];
        us8 h0 = H8[(size_t)s0 * 8 + fl];
        us8 h1 = H8[(size_t)s1 * 8 + fl];
        #pragma unroll
        for (int k = 0; k < 8; ++k)
            a[k] += w0 * bf2f(h0[k]) + w1 * bf2f(h1[k]);
    }
    if (j < end) {
        int s0 = csr_src[j];
        float w0 = dinv[s0];
        us8 h0 = H8[(size_t)s0 * 8 + fl];
        #pragma unroll
        for (int k = 0; k < 8; ++k)
            a[k] += w0 * bf2f(h0[k]);
    }
    float dd = dinv[wid];
    if (grp == 0) {   // self loop, weight dd
        us8 hs = H8[(size_t)wid * 8 + fl];
        #pragma unroll
        for (int k = 0; k < 8; ++k)
            a[k] += dd * bf2f(hs[k]);
    }
    // reduce across the 8 edge groups (xor bits 3,4,5)
    #pragma unroll
    for (int off = 8; off < 64; off <<= 1)
        #pragma unroll
        for (int k = 0; k < 8; ++k)
            a[k] += __shfl_xor(a[k], off);
    #pragma unroll
    for (int k = 0; k < 8; ++k) a[k] *= dd;

    // bias + relu
    float4 b0 = *reinterpret_cast<const float4*>(b + fl * 8);
    float4 b1v = *reinterpret_cast<const float4*>(b + fl * 8 + 4);
    a[0] = fmaxf(a[0] + b0.x, 0.f); a[1] = fmaxf(a[1] + b0.y, 0.f);
    a[2] = fmaxf(a[2] + b0.z, 0.f); a[3] = fmaxf(a[3] + b0.w, 0.f);
    a[4] = fmaxf(a[4] + b1v.x, 0.f); a[5] = fmaxf(a[5] + b1v.y, 0.f);
    a[6] = fmaxf(a[6] + b1v.z, 0.f); a[7] = fmaxf(a[7] + b1v.w, 0.f);

    float s = 0.f;
    #pragma unroll
    for (int k = 0; k < 8; ++k) s += a[k];
    #pragma unroll
    for (int off = 1; off < 8; off <<= 1) s += __shfl_xor(s, off);
    float mu = s * (1.0f / 64.0f);
    float vs = 0.f;
    #pragma unroll
    for (int k = 0; k < 8; ++k) {
        float d = a[k] - mu;
        vs += d * d;
    }
    #pragma unroll
    for (int off = 1; off < 8; off <<= 1) vs += __shfl_xor(vs, off);
    float r = rsqrtf(vs * (1.0f / 64.0f) + LN_EPS);

    if (grp == 0) {
        float4 g0 = *reinterpret_cast<const float4*>(g + fl * 8);
        float4 g1 = *reinterpret_cast<const float4*>(g + fl * 8 + 4);
        float4 e0 = *reinterpret_cast<const float4*>(beta + fl * 8);
        float4 e1 = *reinterpret_cast<const float4*>(beta + fl * 8 + 4);
        float4 o0, o1;
        o0.x = (a[0] - mu) * r * g0.x + e0.x;
        o0.y = (a[1] - mu) * r * g0.y + e0.y;
        o0.z = (a[2] - mu) * r * g0.z + e0.z;
        o0.w = (a[3] - mu) * r * g0.w + e0.w;
        o1.x = (a[4] - mu) * r * g1.x + e1.x;
        o1.y = (a[5] - mu) * r * g1.y + e1.y;
        o1.z = (a[6] - mu) * r * g1.z + e1.z;
        o1.w = (a[7] - mu) * r * g1.w + e1.w;
        float4* out4 = reinterpret_cast<float4*>(out + (size_t)wid * 64 + fl * 8);
        out4[0] = o0;
        out4[1] = o1;
    }
}

extern "C" void kernel_launch(void* const* d_in, const int* in_sizes, int n_in,
                              void* d_out, int out_size, void* d_ws, size_t ws_size,
                              hipStream_t stream) {
    const float* z     = (const float*)d_in[0];
    const int*   ei    = (const int*)d_in[1];
    const float* W1    = (const float*)d_in[2];
    const float* b1    = (const float*)d_in[3];
    const float* g1    = (const float*)d_in[4];
    const float* beta1 = (const float*)d_in[5];
    const float* W2    = (const float*)d_in[6];
    const float* b2    = (const float*)d_in[7];
    const float* g2    = (const float*)d_in[8];
    const float* beta2 = (const float*)d_in[9];
    const float* Wm1   = (const float*)d_in[10];
    const float* bm1   = (const float*)d_in[11];
    const float* Wm2   = (const float*)d_in[12];
    const float* bm2   = (const float*)d_in[13];

    int N = in_sizes[0] / 64;
    int E = in_sizes[1] / 2;
    const int* src = ei;
    const int* dst = ei + E;
    float* out = (float*)d_out;

    int NB  = (N + 255) >> 8;          // buckets (dst>>8)
    int NB1 = (E + EPB - 1) / EPB;     // edge blocks

    size_t N64 = (size_t)N * 64;
    auto rnd = [](size_t x) { return (x + 1023) & ~(size_t)1023; };
    int*   bbase     = (int*)d_ws;                       // NB+1
    int*   btot      = bbase + rnd(NB + 1);              // NB
    int*   blockhist = btot + rnd(NB);                   // NB1*NB
    int*   entries   = blockhist + rnd((size_t)NB1 * NB);// E
    int*   row_ptr   = entries + rnd(E);                 // N+1
    float* dinv      = (float*)(row_ptr + rnd(N + 1));   // N
    int*   csr_src   = (int*)(dinv + rnd(N));            // E
    u16*   Hb        = (u16*)(csr_src + rnd(E));         // N*64 bf16
    float* B3        = (float*)(Hb + rnd(N64));          // N*64 fp32

    int nb_g = (N + 63) / 64;
    int nb_w = (N * 64 + 255) / 256;
    size_t lds_nb = (size_t)NB * sizeof(int);

    // ---- CSR build (two-level counting sort) ----
    k_p1_hist<<<NB1, 256, lds_nb, stream>>>(dst, blockhist, E, NB);
    k_p2a<<<NB, 512, 0, stream>>>(blockhist, btot, NB, NB1);
    k_p2b<<<1, 512, 0, stream>>>(btot, bbase, row_ptr, NB, N, E);
    k_p3_scatter<<<NB1, 256, lds_nb, stream>>>(src, dst, blockhist, bbase, entries, E, NB);
    k_p4_csr<<<NB, 256, 0, stream>>>(entries, bbase, row_ptr, dinv, csr_src, N);

    // ---- layer 1 ----
    k_gemm64_bf16<<<nb_g, 256, 0, stream>>>(z, W1, Hb, N);
    k_gather_ln<<<nb_w, 256, 0, stream>>>(Hb, row_ptr, csr_src, dinv, b1, g1, beta1, B3, N);
    // ---- layer 2 ----
    k_gemm64_bf16<<<nb_g, 256, 0, stream>>>(B3, W2, Hb, N);
    k_gather_ln<<<nb_w, 256, 0, stream>>>(Hb, row_ptr, csr_src, dinv, b2, g2, beta2, B3, N);
    // ---- fused MLP head ----
    k_gemm_mlp<<<nb_g, 256, 0, stream>>>(B3, Wm1, bm1, Wm2, bm2, out, N);
}

// Round 7
// 225.030 us; speedup vs baseline: 4.2575x; 1.1377x over previous
//
#include <hip/hip_runtime.h>
#include <hip/hip_bf16.h>

#define LN_EPS 1e-5f
#define EPB 4096          // edges per block in bucket passes
typedef unsigned short u16;
typedef unsigned short us8 __attribute__((ext_vector_type(8)));

static __device__ __forceinline__ float bf2f(u16 x) {
    return __uint_as_float(((unsigned int)x) << 16);
}
static __device__ __forceinline__ u16 f2bf(float f) {
    unsigned int u = __float_as_uint(f);
    return (u16)((u + 0x7fff + ((u >> 16) & 1)) >> 16);  // RNE
}

// ================= CSR build: two-level counting sort (bucket = dst>>8) =================
__global__ __launch_bounds__(256) void k_p1_hist(const int* __restrict__ dst,
                                                 int* __restrict__ blockhist,
                                                 int E, int NB) {
    extern __shared__ int h[];
    int b = blockIdx.x, t = threadIdx.x;
    for (int j = t; j < NB; j += 256) h[j] = 0;
    __syncthreads();
    int e0 = b * EPB, e1 = min(E, e0 + EPB);
    for (int e = e0 + t; e < e1; e += 256)
        atomicAdd(&h[dst[e] >> 8], 1);
    __syncthreads();
    for (int j = t; j < NB; j += 256)
        blockhist[(size_t)b * NB + j] = h[j];
}

__global__ __launch_bounds__(512) void k_p2a(int* __restrict__ blockhist,
                                             int* __restrict__ btot, int NB, int NB1) {
    __shared__ int sd[512];
    int k = blockIdx.x, t = threadIdx.x;
    int v = (t < NB1) ? blockhist[(size_t)t * NB + k] : 0;
    sd[t] = v;
    __syncthreads();
    for (int off = 1; off < 512; off <<= 1) {
        int x = (t >= off) ? sd[t - off] : 0;
        __syncthreads();
        sd[t] += x;
        __syncthreads();
    }
    if (t < NB1) blockhist[(size_t)t * NB + k] = sd[t] - v;
    if (t == 511) btot[k] = sd[511];
}

__global__ __launch_bounds__(512) void k_p2b(const int* __restrict__ btot,
                                             int* __restrict__ bbase,
                                             int* __restrict__ row_ptr,
                                             int NB, int N, int E) {
    __shared__ int sd[512];
    int t = threadIdx.x;
    int v = (t < NB) ? btot[t] : 0;
    sd[t] = v;
    __syncthreads();
    for (int off = 1; off < 512; off <<= 1) {
        int x = (t >= off) ? sd[t - off] : 0;
        __syncthreads();
        sd[t] += x;
        __syncthreads();
    }
    if (t < NB) bbase[t] = sd[t] - v;
    if (t == 0) { bbase[NB] = E; row_ptr[N] = E; }
}

__global__ __launch_bounds__(256) void k_p3_scatter(const int* __restrict__ src,
                                                    const int* __restrict__ dst,
                                                    const int* __restrict__ blockhist,
                                                    const int* __restrict__ bbase,
                                                    int* __restrict__ entries,
                                                    int E, int NB) {
    extern __shared__ int cur[];
    int b = blockIdx.x, t = threadIdx.x;
    for (int j = t; j < NB; j += 256)
        cur[j] = bbase[j] + blockhist[(size_t)b * NB + j];
    __syncthreads();
    int e0 = b * EPB, e1 = min(E, e0 + EPB);
    for (int e = e0 + t; e < e1; e += 256) {
        int d = dst[e];
        int p = atomicAdd(&cur[d >> 8], 1);
        entries[p] = (src[e] << 8) | (d & 255);
    }
}

__global__ __launch_bounds__(256) void k_p4_csr(const int* __restrict__ entries,
                                                const int* __restrict__ bbase,
                                                int* __restrict__ row_ptr,
                                                float* __restrict__ dinv,
                                                int* __restrict__ csr_src, int N) {
    __shared__ int hist[256];
    __shared__ int sd[256];
    __shared__ int cur[256];
    int k = blockIdx.x, t = threadIdx.x;
    int b0 = bbase[k], b1 = bbase[k + 1];
    hist[t] = 0;
    __syncthreads();
    for (int e = b0 + t; e < b1; e += 256)
        atomicAdd(&hist[entries[e] & 255], 1);
    __syncthreads();
    int v = hist[t];
    sd[t] = v;
    __syncthreads();
    for (int off = 1; off < 256; off <<= 1) {
        int x = (t >= off) ? sd[t - off] : 0;
        __syncthreads();
        sd[t] += x;
        __syncthreads();
    }
    int excl = sd[t] - v;
    int node = (k << 8) + t;
    if (node < N) {
        row_ptr[node] = b0 + excl;
        dinv[node] = rsqrtf(1.0f + (float)v);
    }
    cur[t] = b0 + excl;
    __syncthreads();
    for (int e = b0 + t; e < b1; e += 256) {
        int en = entries[e];
        int p = atomicAdd(&cur[en & 255], 1);
        csr_src[p] = en >> 8;
    }
}

// ===== dense GEMM: C[N][64] = (A[N][64] @ W[64][64]) * dinv[n]  (bf16 out) =====
__global__ __launch_bounds__(256) void k_gemm64_bf16(const float* __restrict__ A,
                                                     const float* __restrict__ W,
                                                     const float* __restrict__ dinv,
                                                     u16* __restrict__ C, int N) {
    __shared__ __align__(16) float As[64][68];
    __shared__ __align__(16) float Ws[64][68];
    int tid = threadIdx.x;
    int n0 = blockIdx.x * 64;

    #pragma unroll
    for (int p = 0; p < 4; ++p) {
        int flat = p * 1024 + tid * 4;
        int r = flat >> 6, c = flat & 63;
        float4 w = *reinterpret_cast<const float4*>(W + flat);
        *reinterpret_cast<float4*>(&Ws[r][c]) = w;
        int node = n0 + r;
        float4 a = make_float4(0.f, 0.f, 0.f, 0.f);
        if (node < N) a = *reinterpret_cast<const float4*>(A + (size_t)node * 64 + c);
        *reinterpret_cast<float4*>(&As[r][c]) = a;
    }
    __syncthreads();

    int tx = tid & 15;
    int ty = tid >> 4;
    float acc[4][4];
    #pragma unroll
    for (int i = 0; i < 4; ++i)
        #pragma unroll
        for (int j = 0; j < 4; ++j) acc[i][j] = 0.f;

    #pragma unroll
    for (int k4 = 0; k4 < 16; ++k4) {
        float4 a[4], w[4];
        #pragma unroll
        for (int ni = 0; ni < 4; ++ni)
            a[ni] = *reinterpret_cast<const float4*>(&As[ty * 4 + ni][k4 * 4]);
        #pragma unroll
        for (int j = 0; j < 4; ++j)
            w[j] = *reinterpret_cast<const float4*>(&Ws[k4 * 4 + j][tx * 4]);
        #pragma unroll
        for (int ni = 0; ni < 4; ++ni) {
            const float* av = reinterpret_cast<const float*>(&a[ni]);
            #pragma unroll
            for (int j = 0; j < 4; ++j) {
                float ak = av[j];
                acc[ni][0] += ak * w[j].x;
                acc[ni][1] += ak * w[j].y;
                acc[ni][2] += ak * w[j].z;
                acc[ni][3] += ak * w[j].w;
            }
        }
    }

    #pragma unroll
    for (int ni = 0; ni < 4; ++ni) {
        int node = n0 + ty * 4 + ni;
        if (node < N) {
            float s = dinv[node];
            ushort4 cb;
            cb.x = f2bf(acc[ni][0] * s); cb.y = f2bf(acc[ni][1] * s);
            cb.z = f2bf(acc[ni][2] * s); cb.w = f2bf(acc[ni][3] * s);
            *reinterpret_cast<ushort4*>(C + (size_t)node * 64 + tx * 4) = cb;
        }
    }
}

// ===== fused MLP head: out[N][3] = relu(A @ Wm1 + bm1) @ Wm2 + bm2 =====
__global__ __launch_bounds__(256) void k_gemm_mlp(const float* __restrict__ A,
                                                  const float* __restrict__ W,
                                                  const float* __restrict__ bias,
                                                  const float* __restrict__ Wm2,
                                                  const float* __restrict__ bm2,
                                                  float* __restrict__ out, int N) {
    __shared__ __align__(16) float As[64][68];
    __shared__ __align__(16) float Ws[64][68];
    int tid = threadIdx.x;
    int n0 = blockIdx.x * 64;

    #pragma unroll
    for (int p = 0; p < 4; ++p) {
        int flat = p * 1024 + tid * 4;
        int r = flat >> 6, c = flat & 63;
        float4 w = *reinterpret_cast<const float4*>(W + flat);
        *reinterpret_cast<float4*>(&Ws[r][c]) = w;
        int node = n0 + r;
        float4 a = make_float4(0.f, 0.f, 0.f, 0.f);
        if (node < N) a = *reinterpret_cast<const float4*>(A + (size_t)node * 64 + c);
        *reinterpret_cast<float4*>(&As[r][c]) = a;
    }
    __syncthreads();

    int tx = tid & 15;
    int ty = tid >> 4;
    float acc[4][4];
    #pragma unroll
    for (int i = 0; i < 4; ++i)
        #pragma unroll
        for (int j = 0; j < 4; ++j) acc[i][j] = 0.f;

    #pragma unroll
    for (int k4 = 0; k4 < 16; ++k4) {
        float4 a[4], w[4];
        #pragma unroll
        for (int ni = 0; ni < 4; ++ni)
            a[ni] = *reinterpret_cast<const float4*>(&As[ty * 4 + ni][k4 * 4]);
        #pragma unroll
        for (int j = 0; j < 4; ++j)
            w[j] = *reinterpret_cast<const float4*>(&Ws[k4 * 4 + j][tx * 4]);
        #pragma unroll
        for (int ni = 0; ni < 4; ++ni) {
            const float* av = reinterpret_cast<const float*>(&a[ni]);
            #pragma unroll
            for (int j = 0; j < 4; ++j) {
                float ak = av[j];
                acc[ni][0] += ak * w[j].x;
                acc[ni][1] += ak * w[j].y;
                acc[ni][2] += ak * w[j].z;
                acc[ni][3] += ak * w[j].w;
            }
        }
    }

    float4 bv = *reinterpret_cast<const float4*>(bias + tx * 4);
    #pragma unroll
    for (int ni = 0; ni < 4; ++ni) {
        acc[ni][0] = fmaxf(acc[ni][0] + bv.x, 0.f);
        acc[ni][1] = fmaxf(acc[ni][1] + bv.y, 0.f);
        acc[ni][2] = fmaxf(acc[ni][2] + bv.z, 0.f);
        acc[ni][3] = fmaxf(acc[ni][3] + bv.w, 0.f);
    }

    float wm[4][3];
    #pragma unroll
    for (int j = 0; j < 4; ++j)
        #pragma unroll
        for (int c = 0; c < 3; ++c)
            wm[j][c] = Wm2[(tx * 4 + j) * 3 + c];
    float p[4][3];
    #pragma unroll
    for (int ni = 0; ni < 4; ++ni) {
        #pragma unroll
        for (int c = 0; c < 3; ++c) {
            p[ni][c] = acc[ni][0] * wm[0][c] + acc[ni][1] * wm[1][c] +
                       acc[ni][2] * wm[2][c] + acc[ni][3] * wm[3][c];
        }
    }
    #pragma unroll
    for (int off = 1; off < 16; off <<= 1)
        #pragma unroll
        for (int ni = 0; ni < 4; ++ni)
            #pragma unroll
            for (int c = 0; c < 3; ++c)
                p[ni][c] += __shfl_xor(p[ni][c], off);
    if (tx == 0) {
        #pragma unroll
        for (int ni = 0; ni < 4; ++ni) {
            int node = n0 + ty * 4 + ni;
            if (node < N) {
                out[(size_t)node * 3 + 0] = p[ni][0] + bm2[0];
                out[(size_t)node * 3 + 1] = p[ni][1] + bm2[1];
                out[(size_t)node * 3 + 2] = p[ni][2] + bm2[2];
            }
        }
    }
}

// ===== gather: 8 nodes/wave, one 8-lane group per node; rows pre-scaled by dinv =====
// Hb[s] = H[s]*dinv[s].  AGG[d] = dd * ( sum_nbr Hb[s] + Hb[d] )
//   neighbor: dd*dinv[s]*H[s] ✓     self: dd*Hb[d] = dd^2*H[d] ✓
__global__ __launch_bounds__(256) void k_gather_ln(const u16* __restrict__ Hb,
                                                   const int* __restrict__ row_ptr,
                                                   const int* __restrict__ csr_src,
                                                   const float* __restrict__ dinv,
                                                   const float* __restrict__ b,
                                                   const float* __restrict__ g,
                                                   const float* __restrict__ beta,
                                                   float* __restrict__ out, int N) {
    int tid = blockIdx.x * blockDim.x + threadIdx.x;
    int node = tid >> 3;         // one 8-lane group per node
    if (node >= N) return;
    int fl = threadIdx.x & 7;    // feature octet: feats 8*fl .. 8*fl+7
    const us8* H8 = reinterpret_cast<const us8*>(Hb);

    float a[8];
    #pragma unroll
    for (int k = 0; k < 8; ++k) a[k] = 0.f;

    int beg = row_ptr[node], end = row_ptr[node + 1];
    int j = beg;
    for (; j + 2 <= end; j += 2) {
        int s0 = csr_src[j];
        int s1 = csr_src[j + 1];
        us8 h0 = H8[(size_t)s0 * 8 + fl];
        us8 h1 = H8[(size_t)s1 * 8 + fl];
        #pragma unroll
        for (int k = 0; k < 8; ++k)
            a[k] += bf2f(h0[k]) + bf2f(h1[k]);
    }
    if (j < end) {
        int s0 = csr_src[j];
        us8 h0 = H8[(size_t)s0 * 8 + fl];
        #pragma unroll
        for (int k = 0; k < 8; ++k)
            a[k] += bf2f(h0[k]);
    }
    float dd = dinv[node];
    {   // self loop: rows pre-scaled, so just += Hb[d]  (NO extra dd factor)
        us8 hs = H8[(size_t)node * 8 + fl];
        #pragma unroll
        for (int k = 0; k < 8; ++k)
            a[k] += bf2f(hs[k]);
    }
    #pragma unroll
    for (int k = 0; k < 8; ++k) a[k] *= dd;

    // bias + relu
    float4 b0 = *reinterpret_cast<const float4*>(b + fl * 8);
    float4 b1v = *reinterpret_cast<const float4*>(b + fl * 8 + 4);
    a[0] = fmaxf(a[0] + b0.x, 0.f); a[1] = fmaxf(a[1] + b0.y, 0.f);
    a[2] = fmaxf(a[2] + b0.z, 0.f); a[3] = fmaxf(a[3] + b0.w, 0.f);
    a[4] = fmaxf(a[4] + b1v.x, 0.f); a[5] = fmaxf(a[5] + b1v.y, 0.f);
    a[6] = fmaxf(a[6] + b1v.z, 0.f); a[7] = fmaxf(a[7] + b1v.w, 0.f);

    // LN across 64 feats = 8 lanes x 8; group-local shuffles (offsets 1,2,4)
    float s = 0.f;
    #pragma unroll
    for (int k = 0; k < 8; ++k) s += a[k];
    s += __shfl_xor(s, 1); s += __shfl_xor(s, 2); s += __shfl_xor(s, 4);
    float mu = s * (1.0f / 64.0f);
    float vs = 0.f;
    #pragma unroll
    for (int k = 0; k < 8; ++k) {
        float d = a[k] - mu;
        vs += d * d;
    }
    vs += __shfl_xor(vs, 1); vs += __shfl_xor(vs, 2); vs += __shfl_xor(vs, 4);
    float r = rsqrtf(vs * (1.0f / 64.0f) + LN_EPS);

    float4 g0 = *reinterpret_cast<const float4*>(g + fl * 8);
    float4 g1 = *reinterpret_cast<const float4*>(g + fl * 8 + 4);
    float4 e0 = *reinterpret_cast<const float4*>(beta + fl * 8);
    float4 e1 = *reinterpret_cast<const float4*>(beta + fl * 8 + 4);
    float4 o0, o1;
    o0.x = (a[0] - mu) * r * g0.x + e0.x;
    o0.y = (a[1] - mu) * r * g0.y + e0.y;
    o0.z = (a[2] - mu) * r * g0.z + e0.z;
    o0.w = (a[3] - mu) * r * g0.w + e0.w;
    o1.x = (a[4] - mu) * r * g1.x + e1.x;
    o1.y = (a[5] - mu) * r * g1.y + e1.y;
    o1.z = (a[6] - mu) * r * g1.z + e1.z;
    o1.w = (a[7] - mu) * r * g1.w + e1.w;
    float4* out4 = reinterpret_cast<float4*>(out + (size_t)node * 64 + fl * 8);
    out4[0] = o0;
    out4[1] = o1;
}

extern "C" void kernel_launch(void* const* d_in, const int* in_sizes, int n_in,
                              void* d_out, int out_size, void* d_ws, size_t ws_size,
                              hipStream_t stream) {
    const float* z     = (const float*)d_in[0];
    const int*   ei    = (const int*)d_in[1];
    const float* W1    = (const float*)d_in[2];
    const float* b1    = (const float*)d_in[3];
    const float* g1    = (const float*)d_in[4];
    const float* beta1 = (const float*)d_in[5];
    const float* W2    = (const float*)d_in[6];
    const float* b2    = (const float*)d_in[7];
    const float* g2    = (const float*)d_in[8];
    const float* beta2 = (const float*)d_in[9];
    const float* Wm1   = (const float*)d_in[10];
    const float* bm1   = (const float*)d_in[11];
    const float* Wm2   = (const float*)d_in[12];
    const float* bm2   = (const float*)d_in[13];

    int N = in_sizes[0] / 64;
    int E = in_sizes[1] / 2;
    const int* src = ei;
    const int* dst = ei + E;
    float* out = (float*)d_out;

    int NB  = (N + 255) >> 8;          // buckets (dst>>8)
    int NB1 = (E + EPB - 1) / EPB;     // edge blocks

    size_t N64 = (size_t)N * 64;
    auto rnd = [](size_t x) { return (x + 1023) & ~(size_t)1023; };
    int*   bbase     = (int*)d_ws;                       // NB+1
    int*   btot      = bbase + rnd(NB + 1);              // NB
    int*   blockhist = btot + rnd(NB);                   // NB1*NB
    int*   entries   = blockhist + rnd((size_t)NB1 * NB);// E
    int*   row_ptr   = entries + rnd(E);                 // N+1
    float* dinv      = (float*)(row_ptr + rnd(N + 1));   // N
    int*   csr_src   = (int*)(dinv + rnd(N));            // E
    u16*   Hb        = (u16*)(csr_src + rnd(E));         // N*64 bf16
    float* B3        = (float*)(Hb + rnd(N64));          // N*64 fp32

    int nb_g = (N + 63) / 64;
    int nb_gw = (N * 8 + 255) / 256;   // 8 lanes per node
    size_t lds_nb = (size_t)NB * sizeof(int);

    // ---- CSR build (two-level counting sort) ----
    k_p1_hist<<<NB1, 256, lds_nb, stream>>>(dst, blockhist, E, NB);
    k_p2a<<<NB, 512, 0, stream>>>(blockhist, btot, NB, NB1);
    k_p2b<<<1, 512, 0, stream>>>(btot, bbase, row_ptr, NB, N, E);
    k_p3_scatter<<<NB1, 256, lds_nb, stream>>>(src, dst, blockhist, bbase, entries, E, NB);
    k_p4_csr<<<NB, 256, 0, stream>>>(entries, bbase, row_ptr, dinv, csr_src, N);

    // ---- layer 1 ----
    k_gemm64_bf16<<<nb_g, 256, 0, stream>>>(z, W1, dinv, Hb, N);
    k_gather_ln<<<nb_gw, 256, 0, stream>>>(Hb, row_ptr, csr_src, dinv, b1, g1, beta1, B3, N);
    // ---- layer 2 ----
    k_gemm64_bf16<<<nb_g, 256, 0, stream>>>(B3, W2, dinv, Hb, N);
    k_gather_ln<<<nb_gw, 256, 0, stream>>>(Hb, row_ptr, csr_src, dinv, b2, g2, beta2, B3, N);
    // ---- fused MLP head ----
    k_gemm_mlp<<<nb_g, 256, 0, stream>>>(B3, Wm1, bm1, Wm2, bm2, out, N);
}

// Round 8
// 168.101 us; speedup vs baseline: 5.6993x; 1.3387x over previous
//
#include <hip/hip_runtime.h>
#include <hip/hip_bf16.h>

#define LN_EPS 1e-5f
#define EPB 4096          // edges per block in bucket passes
typedef unsigned short u16;
typedef unsigned short us8 __attribute__((ext_vector_type(8)));
typedef short s8v __attribute__((ext_vector_type(8)));   // 8 bf16 (4 VGPRs) MFMA frag
typedef float f32x4 __attribute__((ext_vector_type(4))); // MFMA acc

static __device__ __forceinline__ float bf2f(u16 x) {
    return __uint_as_float(((unsigned int)x) << 16);
}
static __device__ __forceinline__ u16 f2bf(float f) {
    unsigned int u = __float_as_uint(f);
    return (u16)((u + 0x7fff + ((u >> 16) & 1)) >> 16);  // RNE
}

// ================= CSR build: two-level counting sort (bucket = dst>>8) =================
__global__ __launch_bounds__(256) void k_p1_hist(const int* __restrict__ dst,
                                                 int* __restrict__ blockhist,
                                                 int E, int NB) {
    extern __shared__ int h[];
    int b = blockIdx.x, t = threadIdx.x;
    for (int j = t; j < NB; j += 256) h[j] = 0;
    __syncthreads();
    int e0 = b * EPB, e1 = min(E, e0 + EPB);
    for (int e = e0 + t; e < e1; e += 256)
        atomicAdd(&h[dst[e] >> 8], 1);
    __syncthreads();
    for (int j = t; j < NB; j += 256)
        blockhist[(size_t)b * NB + j] = h[j];
}

__global__ __launch_bounds__(512) void k_p2a(int* __restrict__ blockhist,
                                             int* __restrict__ btot, int NB, int NB1) {
    __shared__ int sd[512];
    int k = blockIdx.x, t = threadIdx.x;
    int v = (t < NB1) ? blockhist[(size_t)t * NB + k] : 0;
    sd[t] = v;
    __syncthreads();
    for (int off = 1; off < 512; off <<= 1) {
        int x = (t >= off) ? sd[t - off] : 0;
        __syncthreads();
        sd[t] += x;
        __syncthreads();
    }
    if (t < NB1) blockhist[(size_t)t * NB + k] = sd[t] - v;
    if (t == 511) btot[k] = sd[511];
}

__global__ __launch_bounds__(512) void k_p2b(const int* __restrict__ btot,
                                             int* __restrict__ bbase,
                                             int* __restrict__ row_ptr,
                                             int NB, int N, int E) {
    __shared__ int sd[512];
    int t = threadIdx.x;
    int v = (t < NB) ? btot[t] : 0;
    sd[t] = v;
    __syncthreads();
    for (int off = 1; off < 512; off <<= 1) {
        int x = (t >= off) ? sd[t - off] : 0;
        __syncthreads();
        sd[t] += x;
        __syncthreads();
    }
    if (t < NB) bbase[t] = sd[t] - v;
    if (t == 0) { bbase[NB] = E; row_ptr[N] = E; }
}

__global__ __launch_bounds__(256) void k_p3_scatter(const int* __restrict__ src,
                                                    const int* __restrict__ dst,
                                                    const int* __restrict__ blockhist,
                                                    const int* __restrict__ bbase,
                                                    int* __restrict__ entries,
                                                    int E, int NB) {
    extern __shared__ int cur[];
    int b = blockIdx.x, t = threadIdx.x;
    for (int j = t; j < NB; j += 256)
        cur[j] = bbase[j] + blockhist[(size_t)b * NB + j];
    __syncthreads();
    int e0 = b * EPB, e1 = min(E, e0 + EPB);
    for (int e = e0 + t; e < e1; e += 256) {
        int d = dst[e];
        int p = atomicAdd(&cur[d >> 8], 1);
        entries[p] = (src[e] << 8) | (d & 255);
    }
}

__global__ __launch_bounds__(256) void k_p4_csr(const int* __restrict__ entries,
                                                const int* __restrict__ bbase,
                                                int* __restrict__ row_ptr,
                                                float* __restrict__ dinv,
                                                int* __restrict__ csr_src, int N) {
    __shared__ int hist[256];
    __shared__ int sd[256];
    __shared__ int cur[256];
    int k = blockIdx.x, t = threadIdx.x;
    int b0 = bbase[k], b1 = bbase[k + 1];
    hist[t] = 0;
    __syncthreads();
    for (int e = b0 + t; e < b1; e += 256)
        atomicAdd(&hist[entries[e] & 255], 1);
    __syncthreads();
    int v = hist[t];
    sd[t] = v;
    __syncthreads();
    for (int off = 1; off < 256; off <<= 1) {
        int x = (t >= off) ? sd[t - off] : 0;
        __syncthreads();
        sd[t] += x;
        __syncthreads();
    }
    int excl = sd[t] - v;
    int node = (k << 8) + t;
    if (node < N) {
        row_ptr[node] = b0 + excl;
        dinv[node] = rsqrtf(1.0f + (float)v);
    }
    cur[t] = b0 + excl;
    __syncthreads();
    for (int e = b0 + t; e < b1; e += 256) {
        int en = entries[e];
        int p = atomicAdd(&cur[en & 255], 1);
        csr_src[p] = en >> 8;
    }
}

// ===== weight prep: Wtb[m][col][k] = bf16(W_m[k][col]), m in {W1,W2,Wm1} =====
__global__ __launch_bounds__(256) void k_prep_w(const float* __restrict__ W1,
                                                const float* __restrict__ W2,
                                                const float* __restrict__ Wm1,
                                                u16* __restrict__ Wtb) {
    int idx = blockIdx.x * 256 + threadIdx.x;   // 3*4096 total
    if (idx >= 3 * 4096) return;
    int m = idx >> 12;
    int kc = idx & 4095;
    int col = kc >> 6, k = kc & 63;
    const float* W = (m == 0) ? W1 : (m == 1) ? W2 : Wm1;
    Wtb[idx] = f2bf(W[k * 64 + col]);
}

// ===== MFMA GEMM: C[N][64] = (A[N][64] @ W) * dinv[n], bf16 out; wave = 16 nodes =====
// mfma_f32_16x16x32_bf16: A lane: row=l&15, k=(l>>4)*8+j ; B lane: col=l&15, same k
// C/D: col=lane&15, row=(lane>>4)*4+reg  [m89-verified]
template <bool A_FP32>
__global__ __launch_bounds__(256) void k_mfma_gemm(const void* __restrict__ A_,
                                                   const u16* __restrict__ Wtb,
                                                   const float* __restrict__ dinv,
                                                   u16* __restrict__ C, int N) {
    int tid = threadIdx.x;
    int wid = tid >> 6, l = tid & 63;
    int li = l & 15, hi = l >> 4;
    int n0 = blockIdx.x * 64 + wid * 16;
    if (n0 >= N) return;
    int k0 = hi * 8;

    s8v a[2];
    int nr = min(n0 + li, N - 1);
    if (A_FP32) {
        const float* A = (const float*)A_;
        #pragma unroll
        for (int kk = 0; kk < 2; ++kk) {
            const float* p = A + (size_t)nr * 64 + kk * 32 + k0;
            float4 f0 = *reinterpret_cast<const float4*>(p);
            float4 f1 = *reinterpret_cast<const float4*>(p + 4);
            a[kk][0] = (short)f2bf(f0.x); a[kk][1] = (short)f2bf(f0.y);
            a[kk][2] = (short)f2bf(f0.z); a[kk][3] = (short)f2bf(f0.w);
            a[kk][4] = (short)f2bf(f1.x); a[kk][5] = (short)f2bf(f1.y);
            a[kk][6] = (short)f2bf(f1.z); a[kk][7] = (short)f2bf(f1.w);
        }
    } else {
        const u16* A = (const u16*)A_;
        #pragma unroll
        for (int kk = 0; kk < 2; ++kk)
            a[kk] = *reinterpret_cast<const s8v*>(A + (size_t)nr * 64 + kk * 32 + k0);
    }

    s8v b[4][2];
    #pragma unroll
    for (int ct = 0; ct < 4; ++ct)
        #pragma unroll
        for (int kk = 0; kk < 2; ++kk)
            b[ct][kk] = *reinterpret_cast<const s8v*>(Wtb + (ct * 16 + li) * 64 + kk * 32 + k0);

    f32x4 acc[4] = {{0.f, 0.f, 0.f, 0.f}, {0.f, 0.f, 0.f, 0.f},
                    {0.f, 0.f, 0.f, 0.f}, {0.f, 0.f, 0.f, 0.f}};
    #pragma unroll
    for (int kk = 0; kk < 2; ++kk)
        #pragma unroll
        for (int ct = 0; ct < 4; ++ct)
            acc[ct] = __builtin_amdgcn_mfma_f32_16x16x32_bf16(a[kk], b[ct][kk], acc[ct], 0, 0, 0);

    float dv[4];
    #pragma unroll
    for (int r = 0; r < 4; ++r) {
        int node = n0 + hi * 4 + r;
        dv[r] = (node < N) ? dinv[node] : 0.f;
    }
    #pragma unroll
    for (int ct = 0; ct < 4; ++ct)
        #pragma unroll
        for (int r = 0; r < 4; ++r) {
            int node = n0 + hi * 4 + r;
            if (node < N)
                C[(size_t)node * 64 + ct * 16 + li] = f2bf(acc[ct][r] * dv[r]);
        }
}

// ===== MFMA MLP head: out[N][3] = relu(A @ Wm1 + bm1) @ Wm2 + bm2 ; A bf16 =====
__global__ __launch_bounds__(256) void k_mfma_mlp(const u16* __restrict__ A,
                                                  const u16* __restrict__ Wtb,   // Wm1 transposed bf16
                                                  const float* __restrict__ bm1,
                                                  const float* __restrict__ Wm2,
                                                  const float* __restrict__ bm2,
                                                  float* __restrict__ out, int N) {
    int tid = threadIdx.x;
    int wid = tid >> 6, l = tid & 63;
    int li = l & 15, hi = l >> 4;
    int n0 = blockIdx.x * 64 + wid * 16;
    if (n0 >= N) return;
    int k0 = hi * 8;

    s8v a[2];
    int nr = min(n0 + li, N - 1);
    #pragma unroll
    for (int kk = 0; kk < 2; ++kk)
        a[kk] = *reinterpret_cast<const s8v*>(A + (size_t)nr * 64 + kk * 32 + k0);

    s8v b[4][2];
    #pragma unroll
    for (int ct = 0; ct < 4; ++ct)
        #pragma unroll
        for (int kk = 0; kk < 2; ++kk)
            b[ct][kk] = *reinterpret_cast<const s8v*>(Wtb + (ct * 16 + li) * 64 + kk * 32 + k0);

    f32x4 acc[4] = {{0.f, 0.f, 0.f, 0.f}, {0.f, 0.f, 0.f, 0.f},
                    {0.f, 0.f, 0.f, 0.f}, {0.f, 0.f, 0.f, 0.f}};
    #pragma unroll
    for (int kk = 0; kk < 2; ++kk)
        #pragma unroll
        for (int ct = 0; ct < 4; ++ct)
            acc[ct] = __builtin_amdgcn_mfma_f32_16x16x32_bf16(a[kk], b[ct][kk], acc[ct], 0, 0, 0);

    // epilogue: relu(acc + bm1[col]) then project with Wm2[col][0..2]
    float p[4][3];
    #pragma unroll
    for (int r = 0; r < 4; ++r)
        #pragma unroll
        for (int c = 0; c < 3; ++c) p[r][c] = 0.f;

    #pragma unroll
    for (int ct = 0; ct < 4; ++ct) {
        int col = ct * 16 + li;
        float bb = bm1[col];
        float w0 = Wm2[col * 3 + 0], w1 = Wm2[col * 3 + 1], w2 = Wm2[col * 3 + 2];
        #pragma unroll
        for (int r = 0; r < 4; ++r) {
            float v = fmaxf(acc[ct][r] + bb, 0.f);
            p[r][0] += v * w0;
            p[r][1] += v * w1;
            p[r][2] += v * w2;
        }
    }
    // reduce across the 16 lanes sharing the same hi (xor bits 0..3)
    #pragma unroll
    for (int off = 1; off < 16; off <<= 1)
        #pragma unroll
        for (int r = 0; r < 4; ++r)
            #pragma unroll
            for (int c = 0; c < 3; ++c)
                p[r][c] += __shfl_xor(p[r][c], off);

    if (li == 0) {
        float o0 = bm2[0], o1 = bm2[1], o2 = bm2[2];
        #pragma unroll
        for (int r = 0; r < 4; ++r) {
            int node = n0 + hi * 4 + r;
            if (node < N) {
                out[(size_t)node * 3 + 0] = p[r][0] + o0;
                out[(size_t)node * 3 + 1] = p[r][1] + o1;
                out[(size_t)node * 3 + 2] = p[r][2] + o2;
            }
        }
    }
}

// ===== gather: 8 nodes/wave, one 8-lane group per node; rows pre-scaled by dinv =====
// Hb[s] = H[s]*dinv[s].  AGG[d] = dd * ( sum_nbr Hb[s] + Hb[d] ) ; bf16 LN output
__global__ __launch_bounds__(256) void k_gather_ln(const u16* __restrict__ Hb,
                                                   const int* __restrict__ row_ptr,
                                                   const int* __restrict__ csr_src,
                                                   const float* __restrict__ dinv,
                                                   const float* __restrict__ b,
                                                   const float* __restrict__ g,
                                                   const float* __restrict__ beta,
                                                   u16* __restrict__ outb, int N) {
    int tid = blockIdx.x * blockDim.x + threadIdx.x;
    int node = tid >> 3;         // one 8-lane group per node
    if (node >= N) return;
    int fl = threadIdx.x & 7;    // feature octet: feats 8*fl .. 8*fl+7
    const us8* H8 = reinterpret_cast<const us8*>(Hb);

    float a[8];
    #pragma unroll
    for (int k = 0; k < 8; ++k) a[k] = 0.f;

    int beg = row_ptr[node], end = row_ptr[node + 1];
    int j = beg;
    for (; j + 2 <= end; j += 2) {
        int s0 = csr_src[j];
        int s1 = csr_src[j + 1];
        us8 h0 = H8[(size_t)s0 * 8 + fl];
        us8 h1 = H8[(size_t)s1 * 8 + fl];
        #pragma unroll
        for (int k = 0; k < 8; ++k)
            a[k] += bf2f(h0[k]) + bf2f(h1[k]);
    }
    if (j < end) {
        int s0 = csr_src[j];
        us8 h0 = H8[(size_t)s0 * 8 + fl];
        #pragma unroll
        for (int k = 0; k < 8; ++k)
            a[k] += bf2f(h0[k]);
    }
    float dd = dinv[node];
    {   // self loop: rows pre-scaled, so just += Hb[d]
        us8 hs = H8[(size_t)node * 8 + fl];
        #pragma unroll
        for (int k = 0; k < 8; ++k)
            a[k] += bf2f(hs[k]);
    }
    #pragma unroll
    for (int k = 0; k < 8; ++k) a[k] *= dd;

    // bias + relu
    float4 b0 = *reinterpret_cast<const float4*>(b + fl * 8);
    float4 b1v = *reinterpret_cast<const float4*>(b + fl * 8 + 4);
    a[0] = fmaxf(a[0] + b0.x, 0.f); a[1] = fmaxf(a[1] + b0.y, 0.f);
    a[2] = fmaxf(a[2] + b0.z, 0.f); a[3] = fmaxf(a[3] + b0.w, 0.f);
    a[4] = fmaxf(a[4] + b1v.x, 0.f); a[5] = fmaxf(a[5] + b1v.y, 0.f);
    a[6] = fmaxf(a[6] + b1v.z, 0.f); a[7] = fmaxf(a[7] + b1v.w, 0.f);

    // LN across 64 feats = 8 lanes x 8; group-local shuffles (offsets 1,2,4)
    float s = 0.f;
    #pragma unroll
    for (int k = 0; k < 8; ++k) s += a[k];
    s += __shfl_xor(s, 1); s += __shfl_xor(s, 2); s += __shfl_xor(s, 4);
    float mu = s * (1.0f / 64.0f);
    float vs = 0.f;
    #pragma unroll
    for (int k = 0; k < 8; ++k) {
        float d = a[k] - mu;
        vs += d * d;
    }
    vs += __shfl_xor(vs, 1); vs += __shfl_xor(vs, 2); vs += __shfl_xor(vs, 4);
    float r = rsqrtf(vs * (1.0f / 64.0f) + LN_EPS);

    float4 g0 = *reinterpret_cast<const float4*>(g + fl * 8);
    float4 g1 = *reinterpret_cast<const float4*>(g + fl * 8 + 4);
    float4 e0 = *reinterpret_cast<const float4*>(beta + fl * 8);
    float4 e1 = *reinterpret_cast<const float4*>(beta + fl * 8 + 4);
    us8 o;
    o[0] = f2bf((a[0] - mu) * r * g0.x + e0.x);
    o[1] = f2bf((a[1] - mu) * r * g0.y + e0.y);
    o[2] = f2bf((a[2] - mu) * r * g0.z + e0.z);
    o[3] = f2bf((a[3] - mu) * r * g0.w + e0.w);
    o[4] = f2bf((a[4] - mu) * r * g1.x + e1.x);
    o[5] = f2bf((a[5] - mu) * r * g1.y + e1.y);
    o[6] = f2bf((a[6] - mu) * r * g1.z + e1.z);
    o[7] = f2bf((a[7] - mu) * r * g1.w + e1.w);
    *reinterpret_cast<us8*>(outb + (size_t)node * 64 + fl * 8) = o;
}

extern "C" void kernel_launch(void* const* d_in, const int* in_sizes, int n_in,
                              void* d_out, int out_size, void* d_ws, size_t ws_size,
                              hipStream_t stream) {
    const float* z     = (const float*)d_in[0];
    const int*   ei    = (const int*)d_in[1];
    const float* W1    = (const float*)d_in[2];
    const float* b1    = (const float*)d_in[3];
    const float* g1    = (const float*)d_in[4];
    const float* beta1 = (const float*)d_in[5];
    const float* W2    = (const float*)d_in[6];
    const float* b2    = (const float*)d_in[7];
    const float* g2    = (const float*)d_in[8];
    const float* beta2 = (const float*)d_in[9];
    const float* Wm1   = (const float*)d_in[10];
    const float* bm1   = (const float*)d_in[11];
    const float* Wm2   = (const float*)d_in[12];
    const float* bm2   = (const float*)d_in[13];

    int N = in_sizes[0] / 64;
    int E = in_sizes[1] / 2;
    const int* src = ei;
    const int* dst = ei + E;
    float* out = (float*)d_out;

    int NB  = (N + 255) >> 8;          // buckets (dst>>8)
    int NB1 = (E + EPB - 1) / EPB;     // edge blocks

    size_t N64 = (size_t)N * 64;
    auto rnd = [](size_t x) { return (x + 1023) & ~(size_t)1023; };
    int*   bbase     = (int*)d_ws;                       // NB+1
    int*   btot      = bbase + rnd(NB + 1);              // NB
    int*   blockhist = btot + rnd(NB);                   // NB1*NB
    int*   entries   = blockhist + rnd((size_t)NB1 * NB);// E
    int*   row_ptr   = entries + rnd(E);                 // N+1
    float* dinv      = (float*)(row_ptr + rnd(N + 1));   // N
    int*   csr_src   = (int*)(dinv + rnd(N));            // E
    u16*   Hb        = (u16*)(csr_src + rnd(E));         // N*64 bf16 (post-GEMM, dinv-scaled)
    u16*   Hb2       = Hb + rnd(N64);                    // N*64 bf16 (post-LN)
    u16*   Wtb       = Hb2 + rnd(N64);                   // 3*64*64 bf16 transposed weights

    int nb_g = (N + 63) / 64;          // 64 nodes per block (4 waves x 16)
    int nb_gw = (N * 8 + 255) / 256;   // 8 lanes per node
    size_t lds_nb = (size_t)NB * sizeof(int);

    // ---- weight prep + CSR build ----
    k_prep_w<<<48, 256, 0, stream>>>(W1, W2, Wm1, Wtb);
    k_p1_hist<<<NB1, 256, lds_nb, stream>>>(dst, blockhist, E, NB);
    k_p2a<<<NB, 512, 0, stream>>>(blockhist, btot, NB, NB1);
    k_p2b<<<1, 512, 0, stream>>>(btot, bbase, row_ptr, NB, N, E);
    k_p3_scatter<<<NB1, 256, lds_nb, stream>>>(src, dst, blockhist, bbase, entries, E, NB);
    k_p4_csr<<<NB, 256, 0, stream>>>(entries, bbase, row_ptr, dinv, csr_src, N);

    // ---- layer 1 ----
    k_mfma_gemm<true><<<nb_g, 256, 0, stream>>>(z, Wtb, dinv, Hb, N);
    k_gather_ln<<<nb_gw, 256, 0, stream>>>(Hb, row_ptr, csr_src, dinv, b1, g1, beta1, Hb2, N);
    // ---- layer 2 ----
    k_mfma_gemm<false><<<nb_g, 256, 0, stream>>>(Hb2, Wtb + 4096, dinv, Hb, N);
    k_gather_ln<<<nb_gw, 256, 0, stream>>>(Hb, row_ptr, csr_src, dinv, b2, g2, beta2, Hb2, N);
    // ---- fused MLP head ----
    k_mfma_mlp<<<nb_g, 256, 0, stream>>>(Hb2, Wtb + 8192, bm1, Wm2, bm2, out, N);
}